// Round 11
// baseline (576.098 us; speedup 1.0000x reference)
//
#include <hip/hip_runtime.h>
#include <math.h>

// ---------------- constants ----------------
#define BB    8
#define NN    512
#define CIN   64
#define MAXN  16
#define NF    32
#define MID   16
#define BN_   4096        // B*N
#define MSL   65536       // B*N*MAXN
#define MTOT  65568       // MSL + NF
#define RROWS 2098176     // MTOT*NF  (= 8196*256 = 4098*512)
#define P2STR 40          // LDS row stride in ushorts (80 B, 16B-aligned, conflict-free)

typedef unsigned short ushort_t;
typedef __attribute__((ext_vector_type(8))) short bf16x8;
typedef __attribute__((ext_vector_type(4))) float f32x4;

// ---------------- helpers ----------------
__device__ __forceinline__ float mishf(float x){
  float t  = __expf(x);
  float u  = 1.0f + t;
  float u2 = u * u;
  float r  = x * (u2 - 1.0f) * __builtin_amdgcn_rcpf(u2 + 1.0f);
  return (x > 15.0f) ? x : r;
}

__device__ __forceinline__ ushort_t f2bf(float f){
  unsigned u = __float_as_uint(f);
  unsigned r = (u + 0x7FFFu + ((u >> 16) & 1u)) >> 16;   // RNE
  return (ushort_t)r;
}

__device__ __forceinline__ unsigned rotl32(unsigned v, unsigned s){
  return (v << s) | (v >> (32u - s));
}

// threefry2x32(key=(0,42), x=(0,0)) -> bits = out0 ^ out1  [verified: round-3 pass]
__device__ __forceinline__ float jax_uniform42(){
  unsigned ks[3];
  ks[0] = 0u; ks[1] = 42u; ks[2] = 0x1BD11BDAu ^ 0u ^ 42u;
  const unsigned rot[8] = {13u,15u,26u,6u,17u,29u,16u,24u};
  unsigned x0 = ks[0];
  unsigned x1 = ks[1];
  #pragma unroll
  for (int blk = 0; blk < 5; ++blk){
    #pragma unroll
    for (int r = 0; r < 4; ++r){
      x0 += x1;
      x1 = rotl32(x1, rot[(blk & 1) * 4 + r]);
      x1 ^= x0;
    }
    x0 += ks[(blk + 1) % 3];
    x1 += ks[(blk + 2) % 3] + (unsigned)(blk + 1);
  }
  unsigned w = x0 ^ x1;
  return __uint_as_float((w >> 9) | 0x3f800000u) - 1.0f;
}

// ---------------- k_sq: sqd[r] = sum_c x[r][c]^2 in f64 ----------------
__global__ __launch_bounds__(256) void k_sq(const float* __restrict__ x, double* __restrict__ sqd){
  int r = blockIdx.x * 256 + threadIdx.x;
  const float4* p = (const float4*)(x + (size_t)r * 64);
  double a0 = 0.0, a1 = 0.0, a2 = 0.0, a3 = 0.0;
  #pragma unroll
  for (int k = 0; k < 16; k += 4){
    float4 v0 = p[k], v1 = p[k+1], v2 = p[k+2], v3 = p[k+3];
    a0 += (double)v0.x*v0.x + (double)v0.y*v0.y + (double)v0.z*v0.z + (double)v0.w*v0.w;
    a1 += (double)v1.x*v1.x + (double)v1.y*v1.y + (double)v1.z*v1.z + (double)v1.w*v1.w;
    a2 += (double)v2.x*v2.x + (double)v2.y*v2.y + (double)v2.z*v2.z + (double)v2.w*v2.w;
    a3 += (double)v3.x*v3.x + (double)v3.y*v3.y + (double)v3.z*v3.z + (double)v3.w*v3.w;
  }
  sqd[r] = (a0 + a1) + (a2 + a3);
}

// ---------------- kernel 1: feature-space kNN (top-16, f64 distances) ----------------
// Same j-outer structure as R10 (L1-friendly sequential candidate reads); query held
// as f32 regs (64 VGPR) with exact cvt-to-f64 at use -> no scratch spill, results
// bit-identical to the R10-passing version.
__global__ __launch_bounds__(256) void k_topk(const float* __restrict__ x, const double* __restrict__ sqd,
                                              int* __restrict__ idxp){
  __shared__ float xnl[4][64];
  int tid  = threadIdx.x;
  int lane = tid & 63;
  int wid  = tid >> 6;
  int g = blockIdx.x * 4 + wid;
  int b = g >> 9;
  const float* xb = x + (size_t)b * (NN * CIN);
  {
    int w = tid >> 6, c = tid & 63;
    int nq = (blockIdx.x * 4 + w) & 511;
    xnl[w][c] = xb[nq * 64 + c];
  }
  __syncthreads();
  float qf[64];
  #pragma unroll
  for (int c = 0; c < 64; ++c) qf[c] = xnl[wid][c];
  double sqn = sqd[g];

  double dst[8];
  #pragma unroll 1
  for (int j = 0; j < 8; ++j){
    int m = lane + 64 * j;
    const float4* cp = (const float4*)(xb + (size_t)m * 64);
    double d0 = 0.0, d1 = 0.0, d2 = 0.0, d3 = 0.0;
    #pragma unroll
    for (int k = 0; k < 16; ++k){
      float4 v = cp[k];
      d0 += (double)qf[k*4+0] * (double)v.x;
      d1 += (double)qf[k*4+1] * (double)v.y;
      d2 += (double)qf[k*4+2] * (double)v.z;
      d3 += (double)qf[k*4+3] * (double)v.w;
    }
    dst[j] = sqn + sqd[(b << 9) + m] - 2.0 * ((d0 + d1) + (d2 + d3));
  }

  for (int it = 0; it < 16; ++it){
    double bd = 1.0e300; int bi = 0x7FFFFFFF;
    #pragma unroll
    for (int j = 0; j < 8; ++j){
      int m = lane + 64 * j;
      if (dst[j] < bd){ bd = dst[j]; bi = m; }
    }
    #pragma unroll
    for (int off = 1; off < 64; off <<= 1){
      double od = __shfl_xor(bd, off);
      int    oi = __shfl_xor(bi, off);
      if (od < bd || (od == bd && oi < bi)){ bd = od; bi = oi; }
    }
    if (lane == 0) idxp[g * 16 + it] = bi;
    int jj = bi >> 6;
    if (lane == (bi & 63)){
      #pragma unroll
      for (int j = 0; j < 8; ++j) if (j == jj) dst[j] = 1.0e300;
    }
  }
}

// ---------------- k_prep (fused build_sl + proj): sib[i][c], fjt[c][j] ----------------
__global__ __launch_bounds__(256) void k_prep(const float* __restrict__ xyz,
                                              const float* __restrict__ fpts,
                                              const int* __restrict__ idxp,
                                              const float* __restrict__ w0, const float* __restrict__ b0,
                                              float* __restrict__ sib, float* __restrict__ fjt){
  __shared__ float w0l[96], b0l[32];
  int tid = threadIdx.x;
  if (tid < 96) w0l[tid] = w0[tid];
  else if (tid < 128) b0l[tid - 96] = b0[tid - 96];
  __syncthreads();
  int i = blockIdx.x * 256 + tid;
  if (i >= MTOT) return;
  float vx, vy, vz;
  if (i < MSL){
    int bn = i >> 4, m = i & 15, b = bn >> 9;
    int i0 = idxp[bn * 16];
    int im = idxp[bn * 16 + m];
    const float* xz = xyz + (size_t)b * (NN * 3);
    vx = xz[im * 3 + 0] - xz[i0 * 3 + 0];
    vy = xz[im * 3 + 1] - xz[i0 * 3 + 1];
    vz = xz[im * 3 + 2] - xz[i0 * 3 + 2];
  } else {
    int j = i - MSL;
    float u   = jax_uniform42();
    float ang = (u * 2.0f) * 3.14159274f;
    float c = cosf(ang), s = sinf(ang);
    float fx = fpts[j * 3 + 0], fy = fpts[j * 3 + 1], fz = fpts[j * 3 + 2];
    vx = fx * c - fz * s;
    vy = fy;
    vz = fx * s + fz * c;
  }
  float si[32];
  #pragma unroll
  for (int c = 0; c < 32; ++c)
    si[c] = vx * w0l[c] + vy * w0l[32 + c] + vz * w0l[64 + c];
  float* dst = sib + (size_t)i * 32;
  #pragma unroll
  for (int cq = 0; cq < 8; ++cq){
    float4 o = make_float4(si[cq*4+0] + b0l[cq*4+0], si[cq*4+1] + b0l[cq*4+1],
                           si[cq*4+2] + b0l[cq*4+2], si[cq*4+3] + b0l[cq*4+3]);
    *(float4*)&dst[cq*4] = o;
  }
  if (i >= MSL){
    int j = i - MSL;
    #pragma unroll
    for (int c = 0; c < 32; ++c) fjt[c * 32 + j] = si[c];
  }
}

// ---------------- m1 pass 1: stats of mish(L0) ----------------
__global__ __launch_bounds__(256) void k_m1_p1(const float* __restrict__ sib, const float* __restrict__ fjt,
                                               float* __restrict__ s0g, float* __restrict__ q0g){
  __shared__ float fjlt[1024];           // [j][c]
  __shared__ float red[8][32], redq[8][32];
  int tid = threadIdx.x;
  for (int t = tid; t < 1024; t += 256) fjlt[t] = fjt[(t & 31) * 32 + (t >> 5)];
  __syncthreads();
  int c = tid & 31, s = tid >> 5;
  float as = 0.0f, aq = 0.0f;
  size_t base = (size_t)blockIdx.x * 2048;
  #pragma unroll 4
  for (int t = 0; t < 256; ++t){
    size_t r = base + (size_t)t * 8 + s;
    if (r < (size_t)RROWS){
      int i = (int)(r >> 5), j = (int)(r & 31);
      float m = mishf(sib[(size_t)i * 32 + c] - fjlt[j * 32 + c]);
      as += m; aq += m * m;
    }
  }
  red[s][c] = as; redq[s][c] = aq;
  __syncthreads();
  if (tid < 32){
    float ts = 0.0f, tq = 0.0f;
    #pragma unroll
    for (int ss = 0; ss < 8; ++ss){ ts += red[ss][tid]; tq += redq[ss][tid]; }
    int bank = (blockIdx.x & 15) * 32 + tid;
    atomicAdd(&s0g[bank], ts);
    atomicAdd(&q0g[bank], tq);
  }
}

// ---------------- m1 pass 2: bf16 MFMA GEMM (BN0 folded into weights) -> stats + a1b col-major ----------------
__global__ __launch_bounds__(256, 6) void k_m1_p2(const float* __restrict__ sib, const float* __restrict__ fjt,
                                               const float* __restrict__ w1g, const float* __restrict__ b1g,
                                               const float* __restrict__ g0, const float* __restrict__ be0,
                                               const float* __restrict__ s0g, const float* __restrict__ q0g,
                                               float* __restrict__ s1g, float* __restrict__ q1g,
                                               ushort_t* __restrict__ a1b){
  __shared__ __align__(16) ushort_t a0s[256 * P2STR];    // 20480 B, raw mish(a0) in bf16
  __shared__ __align__(16) float uni[1024];              // fjl (staging) then wts bf16 [c][k]
  __shared__ float A0l[32], C0l[32], biasX[32], satm[32], qatm[32];
  ushort_t* wts = (ushort_t*)uni;
  int tid = threadIdx.x;
  // phase 1: fjl + BN0 coefficients
  for (int t = tid; t < 1024; t += 256) uni[t] = fjt[t];
  if (tid < 32){
    float s = 0.0f, q = 0.0f;
    #pragma unroll
    for (int b = 0; b < 16; ++b){ s += s0g[b * 32 + tid]; q += q0g[b * 32 + tid]; }
    const float invR = 1.0f / (float)RROWS;
    float mu = s * invR, var = q * invR - mu * mu;
    float A = g0[tid] * rsqrtf(var + 1e-3f);
    A0l[tid] = A; C0l[tid] = be0[tid] - mu * A;
    satm[tid] = 0.0f; qatm[tid] = 0.0f;
  }
  __syncthreads();
  // phase 2: staging (raw mish -> bf16 LDS) + folded bias
  {
    int r = blockIdx.x * 256 + tid;
    int i = r >> 5, j = r & 31;
    const float* sr = sib + (size_t)i * 32;
    ushort_t* dst = &a0s[tid * P2STR];
    #pragma unroll
    for (int cq = 0; cq < 4; ++cq){
      float4 sa = *(const float4*)&sr[cq * 8];
      float4 sb = *(const float4*)&sr[cq * 8 + 4];
      float m0 = mishf(sa.x - uni[(cq*8+0)*32 + j]);
      float m1 = mishf(sa.y - uni[(cq*8+1)*32 + j]);
      float m2 = mishf(sa.z - uni[(cq*8+2)*32 + j]);
      float m3 = mishf(sa.w - uni[(cq*8+3)*32 + j]);
      float m4 = mishf(sb.x - uni[(cq*8+4)*32 + j]);
      float m5 = mishf(sb.y - uni[(cq*8+5)*32 + j]);
      float m6 = mishf(sb.z - uni[(cq*8+6)*32 + j]);
      float m7 = mishf(sb.w - uni[(cq*8+7)*32 + j]);
      uint4 pk;
      pk.x = (unsigned)f2bf(m0) | ((unsigned)f2bf(m1) << 16);
      pk.y = (unsigned)f2bf(m2) | ((unsigned)f2bf(m3) << 16);
      pk.z = (unsigned)f2bf(m4) | ((unsigned)f2bf(m5) << 16);
      pk.w = (unsigned)f2bf(m6) | ((unsigned)f2bf(m7) << 16);
      *(uint4*)&dst[cq * 8] = pk;
    }
  }
  if (tid < 32){
    float acc = b1g[tid];
    #pragma unroll
    for (int k = 0; k < 32; ++k) acc += C0l[k] * w1g[k * 32 + tid];
    biasX[tid] = acc;
  }
  __syncthreads();
  // phase 3: wts[c][k] = bf16(w1[k][c] * A0[k])   (overwrites fjl area)
  for (int t = tid; t < 1024; t += 256){
    int k = t >> 5, c = t & 31;
    wts[c * P2STR + k] = f2bf(w1g[t] * A0l[k]);
  }
  __syncthreads();
  // phase 4: MFMA. wave w handles m-tiles w*4..w*4+3, n-tiles 0,1
  int lane = tid & 63, w = tid >> 6;
  int ln15 = lane & 15, quad = lane >> 4;
  f32x4 zero = {0.0f, 0.0f, 0.0f, 0.0f};
  bf16x8 bfr0 = *(bf16x8*)&wts[(ln15) * P2STR + quad * 8];
  bf16x8 bfr1 = *(bf16x8*)&wts[(16 + ln15) * P2STR + quad * 8];
  f32x4 acc[4][2];
  #pragma unroll
  for (int i2 = 0; i2 < 4; ++i2){
    int row = (w * 4 + i2) * 16 + ln15;
    bf16x8 af = *(bf16x8*)&a0s[row * P2STR + quad * 8];
    acc[i2][0] = __builtin_amdgcn_mfma_f32_16x16x32_bf16(af, bfr0, zero, 0, 0, 0);
    acc[i2][1] = __builtin_amdgcn_mfma_f32_16x16x32_bf16(af, bfr1, zero, 0, 0, 0);
  }
  // epilogue: mish + col stats + bf16 col-major store (D: col=lane&15, row=quad*4+reg)
  float cs[2] = {0.0f, 0.0f}, cq2[2] = {0.0f, 0.0f};
  size_t rowbase = (size_t)blockIdx.x * 256 + w * 64 + quad * 4;
  #pragma unroll
  for (int nt = 0; nt < 2; ++nt){
    int col = nt * 16 + ln15;
    float bx = biasX[col];
    size_t colbase = (size_t)col * RROWS;
    #pragma unroll
    for (int i2 = 0; i2 < 4; ++i2){
      f32x4 a = acc[i2][nt];
      float m0 = mishf(a[0] + bx);
      float m1 = mishf(a[1] + bx);
      float m2 = mishf(a[2] + bx);
      float m3 = mishf(a[3] + bx);
      cs[nt]  += m0 + m1 + m2 + m3;
      cq2[nt] += m0*m0 + m1*m1 + m2*m2 + m3*m3;
      if (a1b){
        uint2 pk;
        pk.x = (unsigned)f2bf(m0) | ((unsigned)f2bf(m1) << 16);
        pk.y = (unsigned)f2bf(m2) | ((unsigned)f2bf(m3) << 16);
        *(uint2*)&a1b[colbase + rowbase + (size_t)i2 * 16] = pk;
      }
    }
  }
  #pragma unroll
  for (int nt = 0; nt < 2; ++nt){
    float v = cs[nt], u = cq2[nt];
    v += __shfl_xor(v, 16); u += __shfl_xor(u, 16);
    v += __shfl_xor(v, 32); u += __shfl_xor(u, 32);
    if (lane < 16){
      atomicAdd(&satm[nt * 16 + ln15], v);
      atomicAdd(&qatm[nt * 16 + ln15], u);
    }
  }
  __syncthreads();
  if (tid < 32){
    int bank = (blockIdx.x & 15) * 32 + tid;
    atomicAdd(&s1g[bank], satm[tid]);
    atomicAdd(&q1g[bank], qatm[tid]);
  }
}

// ---------------- m1 pass 3 (streaming): a1b col-major, 2 rows/thread ----------------
__global__ __launch_bounds__(256) void k_m1_p3s(const ushort_t* __restrict__ a1b,
                                                const float* __restrict__ w2g, const float* __restrict__ b2g,
                                                const float* __restrict__ g1, const float* __restrict__ be1,
                                                const float* __restrict__ s1g, const float* __restrict__ q1g,
                                                float* __restrict__ act2, float* __restrict__ s2g, float* __restrict__ q2g){
  __shared__ float vvl[32], C1l[32], cb2l[1], r2s[4], r2q[4];
  int tid = threadIdx.x;
  if (tid < 32){
    float s = 0.0f, q = 0.0f;
    #pragma unroll
    for (int b = 0; b < 16; ++b){ s += s1g[b * 32 + tid]; q += q1g[b * 32 + tid]; }
    const float invR = 1.0f / (float)RROWS;
    float mu = s * invR, var = q * invR - mu * mu;
    float A = g1[tid] * rsqrtf(var + 1e-3f);
    C1l[tid] = be1[tid] - mu * A;
    vvl[tid] = A * w2g[tid];
  }
  __syncthreads();
  if (tid == 0){
    float a = b2g[0];
    #pragma unroll
    for (int k = 0; k < 32; ++k) a += C1l[k] * w2g[k];
    cb2l[0] = a;
  }
  __syncthreads();
  size_t r0 = (size_t)blockIdx.x * 512 + (size_t)tid * 2;
  float pre0 = 0.0f, pre1 = 0.0f;
  #pragma unroll
  for (int c = 0; c < 32; ++c){
    unsigned u = *(const unsigned*)&a1b[(size_t)c * RROWS + r0];
    float lo = __uint_as_float(u << 16);
    float hi = __uint_as_float(u & 0xFFFF0000u);
    pre0 += lo * vvl[c];
    pre1 += hi * vvl[c];
  }
  float cb2 = cb2l[0];
  float a20 = mishf(pre0 + cb2);
  float a21 = mishf(pre1 + cb2);
  *(float2*)&act2[r0] = make_float2(a20, a21);
  float ss = a20 + a21, qq = a20*a20 + a21*a21;
  #pragma unroll
  for (int off = 1; off < 64; off <<= 1){ ss += __shfl_xor(ss, off); qq += __shfl_xor(qq, off); }
  int lane = tid & 63, wid = tid >> 6;
  if (lane == 0){ r2s[wid] = ss; r2q[wid] = qq; }
  __syncthreads();
  if (tid == 0){
    atomicAdd(&s2g[blockIdx.x & 15], r2s[0] + r2s[1] + r2s[2] + r2s[3]);
    atomicAdd(&q2g[blockIdx.x & 15], r2q[0] + r2q[1] + r2q[2] + r2q[3]);
  }
}

// ---------------- m1 pass 3 (fallback, recompute) ----------------
__global__ __launch_bounds__(256, 3) void k_m1_p3f(const float* __restrict__ sib, const float* __restrict__ fjt,
                                               const float* __restrict__ w1g, const float* __restrict__ b1g,
                                               const float* __restrict__ g0, const float* __restrict__ be0,
                                               const float* __restrict__ g1, const float* __restrict__ be1,
                                               const float* __restrict__ w2g, const float* __restrict__ b2g,
                                               const float* __restrict__ s0g, const float* __restrict__ q0g,
                                               const float* __restrict__ s1g, const float* __restrict__ q1g,
                                               float* __restrict__ act2, float* __restrict__ s2g, float* __restrict__ q2g){
  __shared__ float fjl[1024];
  __shared__ float w1s[1024];
  __shared__ float A0l[32], C0l[32], A1l[32], C1l[32], biasX[32], vvl[32];
  __shared__ float a0t[32 * 256];
  __shared__ float cb2l[1];
  __shared__ float r2s[4], r2q[4];
  int tid = threadIdx.x;
  const float invR = 1.0f / (float)RROWS;
  for (int t = tid; t < 1024; t += 256) fjl[t] = fjt[t];
  if (tid < 32){
    float s = 0.0f, q = 0.0f;
    #pragma unroll
    for (int b = 0; b < 16; ++b){ s += s0g[b * 32 + tid]; q += q0g[b * 32 + tid]; }
    float mu = s * invR, var = q * invR - mu * mu;
    float A = g0[tid] * rsqrtf(var + 1e-3f);
    A0l[tid] = A; C0l[tid] = be0[tid] - mu * A;
  } else if (tid < 64){
    int c = tid - 32;
    float s = 0.0f, q = 0.0f;
    #pragma unroll
    for (int b = 0; b < 16; ++b){ s += s1g[b * 32 + c]; q += q1g[b * 32 + c]; }
    float mu = s * invR, var = q * invR - mu * mu;
    float A = g1[c] * rsqrtf(var + 1e-3f);
    A1l[c] = A; C1l[c] = be1[c] - mu * A;
  }
  __syncthreads();
  for (int t = tid; t < 1024; t += 256) w1s[t] = w1g[t] * A0l[t >> 5];
  if (tid < 32){
    float acc = b1g[tid];
    #pragma unroll
    for (int k = 0; k < 32; ++k) acc += C0l[k] * w1g[k * 32 + tid];
    biasX[tid] = acc;
  } else if (tid < 96 && tid >= 64){
    int c = tid - 64;
    vvl[c] = A1l[c] * w2g[c];
  } else if (tid == 96){
    float acc = b2g[0];
    #pragma unroll
    for (int k = 0; k < 32; ++k) acc += C1l[k] * w2g[k];
    cb2l[0] = acc;
  }
  {
    int r = blockIdx.x * 256 + tid;
    int i = r >> 5, j = r & 31;
    const float* sr = sib + (size_t)i * 32;
    #pragma unroll
    for (int cq = 0; cq < 8; ++cq){
      float4 sv = *(const float4*)&sr[cq * 4];
      a0t[(cq*4+0)*256 + tid] = mishf(sv.x - fjl[(cq*4+0)*32 + j]);
      a0t[(cq*4+1)*256 + tid] = mishf(sv.y - fjl[(cq*4+1)*32 + j]);
      a0t[(cq*4+2)*256 + tid] = mishf(sv.z - fjl[(cq*4+2)*32 + j]);
      a0t[(cq*4+3)*256 + tid] = mishf(sv.w - fjl[(cq*4+3)*32 + j]);
    }
  }
  __syncthreads();
  int cg = tid & 7, rg = tid >> 3;
  float acc[8][4];
  #pragma unroll
  for (int i2 = 0; i2 < 8; ++i2)
    #pragma unroll
    for (int j2 = 0; j2 < 4; ++j2) acc[i2][j2] = 0.0f;
  #pragma unroll 4
  for (int k = 0; k < 32; ++k){
    float4 w  = *(const float4*)&w1s[k * 32 + cg * 4];
    float4 aA = *(const float4*)&a0t[k * 256 + rg * 8];
    float4 aB = *(const float4*)&a0t[k * 256 + rg * 8 + 4];
    float ar[8] = {aA.x, aA.y, aA.z, aA.w, aB.x, aB.y, aB.z, aB.w};
    float wc[4] = {w.x, w.y, w.z, w.w};
    #pragma unroll
    for (int i2 = 0; i2 < 8; ++i2)
      #pragma unroll
      for (int j2 = 0; j2 < 4; ++j2) acc[i2][j2] += ar[i2] * wc[j2];
  }
  float cb2 = cb2l[0];
  float ss = 0.0f, qq = 0.0f;
  #pragma unroll
  for (int rr = 0; rr < 8; ++rr){
    float part = 0.0f;
    #pragma unroll
    for (int cc = 0; cc < 4; ++cc){
      float m = mishf(acc[rr][cc] + biasX[cg * 4 + cc]);
      part += m * vvl[cg * 4 + cc];
    }
    part += __shfl_xor(part, 1);
    part += __shfl_xor(part, 2);
    part += __shfl_xor(part, 4);
    float a2 = mishf(part + cb2);
    if (cg == 0){
      act2[(size_t)blockIdx.x * 256 + rg * 8 + rr] = a2;
      ss += a2; qq += a2 * a2;
    }
  }
  #pragma unroll
  for (int off = 1; off < 64; off <<= 1){ ss += __shfl_xor(ss, off); qq += __shfl_xor(qq, off); }
  int lane = tid & 63, wid = tid >> 6;
  if (lane == 0){ r2s[wid] = ss; r2q[wid] = qq; }
  __syncthreads();
  if (tid == 0){
    atomicAdd(&s2g[blockIdx.x & 15], r2s[0] + r2s[1] + r2s[2] + r2s[3]);
    atomicAdd(&q2g[blockIdx.x & 15], r2q[0] + r2q[1] + r2q[2] + r2q[3]);
  }
}

// ---------------- m2 MLP layer 1 (K-split) ----------------
__global__ __launch_bounds__(512) void k_wmlp1(const float* __restrict__ fpw, const float* __restrict__ W0,
                                               float* __restrict__ wact0){
  int f = blockIdx.x, kc = blockIdx.y, c = threadIdx.x;
  const float* row = fpw + (size_t)f * 4096 + kc * 512;
  const float* wp  = W0 + (size_t)(kc * 512) * 512 + c;
  float acc = 0.0f;
  #pragma unroll 8
  for (int k = 0; k < 512; ++k) acc += row[k] * wp[(size_t)k * 512];
  atomicAdd(&wact0[f * 512 + c], acc);
}

// ---------------- m2 MLP finish ----------------
__global__ __launch_bounds__(512) void k_wmlp2(const float* __restrict__ wact0, const float* __restrict__ b0,
                                               const float* __restrict__ W1,
                                               const float* __restrict__ b1,
                                               const float* __restrict__ g0, const float* __restrict__ be0,
                                               const float* __restrict__ g1, const float* __restrict__ be1,
                                               float* __restrict__ wfin){
  __shared__ float wl[32 * 512];
  __shared__ float o2l[512], A1l[16], C1l[16];
  int t = threadIdx.x;
  {
    float b0t = b0[t];
    float v[32]; float sum = 0.0f, sq = 0.0f;
    #pragma unroll
    for (int r = 0; r < 32; ++r){
      v[r] = mishf(wact0[r * 512 + t] + b0t);
      sum += v[r]; sq += v[r] * v[r];
    }
    float mu  = sum * (1.0f / 32.0f);
    float var = sq * (1.0f / 32.0f) - mu * mu;
    float A = g0[t] * rsqrtf(var + 1e-3f);
    float C = be0[t] - mu * A;
    #pragma unroll
    for (int r = 0; r < 32; ++r) wl[r * 512 + t] = v[r] * A + C;
  }
  __syncthreads();
  {
    int r = t >> 4, c2 = t & 15;
    float pre = b1[c2];
    for (int k = 0; k < 512; ++k) pre += wl[r * 512 + k] * W1[k * 16 + c2];
    o2l[t] = mishf(pre);
  }
  __syncthreads();
  if (t < 16){
    float sum = 0.0f, sq = 0.0f;
    #pragma unroll
    for (int r = 0; r < 32; ++r){ float v = o2l[r * 16 + t]; sum += v; sq += v * v; }
    float mu  = sum * (1.0f / 32.0f);
    float var = sq * (1.0f / 32.0f) - mu * mu;
    float A = g1[t] * rsqrtf(var + 1e-3f);
    A1l[t] = A; C1l[t] = be1[t] - mu * A;
  }
  __syncthreads();
  wfin[t] = o2l[t] * A1l[t & 15] + C1l[t & 15];
}

// ---------------- aggregation + per-point einsum -> fbuf[4096,1024] ----------------
__global__ __launch_bounds__(256) void k_agg(const float* __restrict__ act2, const float* __restrict__ wfin,
                                             const float* __restrict__ x, const int* __restrict__ idxp,
                                             const float* __restrict__ s2, const float* __restrict__ q2,
                                             const float* __restrict__ g2, const float* __restrict__ be2,
                                             float* __restrict__ fbuf){
  __shared__ float hl[512], wfl[512], wm[256], furl[1024], AC[2];
  int t = threadIdx.x;
  int k = blockIdx.x;
  if (t == 0){
    const float invR = 1.0f / (float)RROWS;
    float ssum = 0.0f, qsum = 0.0f;
    #pragma unroll
    for (int b = 0; b < 16; ++b){ ssum += s2[b]; qsum += q2[b]; }
    float mu  = ssum * invR;
    float var = qsum * invR - mu * mu;
    float A = g2[0] * rsqrtf(var + 1e-3f);
    AC[0] = A; AC[1] = be2[0] - mu * A;
  }
  wfl[t] = wfin[t]; wfl[t + 256] = wfin[t + 256];
  __syncthreads();
  float A2 = AC[0], C2 = AC[1];
  hl[t]       = act2[(size_t)k * 512 + t]       * A2 + C2;
  hl[t + 256] = act2[(size_t)k * 512 + 256 + t] * A2 + C2;
  __syncthreads();
  {
    int m = t >> 4, d = t & 15;
    float acc = 0.0f;
    #pragma unroll
    for (int j = 0; j < 32; ++j) acc += hl[m * 32 + j] * wfl[j * 16 + d];
    wm[t] = acc;
  }
  int b = k >> 9;
  const float* xb = x + (size_t)b * (NN * CIN);
  {
    int c = t & 63;
    #pragma unroll
    for (int it = 0; it < 4; ++it){
      int m = it * 4 + (t >> 6);
      int im = idxp[k * 16 + m];
      furl[m * 64 + c] = xb[im * 64 + c];
    }
  }
  __syncthreads();
  {
    int d = t & 15, c0 = t >> 4;
    #pragma unroll
    for (int q = 0; q < 4; ++q){
      int c = c0 + 16 * q;
      float acc = 0.0f;
      #pragma unroll
      for (int m = 0; m < 16; ++m) acc += furl[m * 64 + c] * wm[m * 16 + d];
      fbuf[(size_t)k * 1024 + t + 256 * q] = acc;
    }
  }
}

// ---------------- mr layer 1 ----------------
__global__ __launch_bounds__(256) void k_mr1(const float* __restrict__ F, const float* __restrict__ W,
                                             const float* __restrict__ bias, float* __restrict__ out,
                                             float* __restrict__ s3, float* __restrict__ q3){
  __shared__ float As[16][68];
  __shared__ float Bs[16][68];
  __shared__ float csum[64], csq[64];
  int tid = threadIdx.x;
  int m0 = blockIdx.y * 64, n0 = blockIdx.x * 64;
  int tx = tid & 15, ty = tid >> 4;
  if (tid < 64){ csum[tid] = 0.0f; csq[tid] = 0.0f; }
  float acc[4][4];
  #pragma unroll
  for (int i = 0; i < 4; ++i)
    #pragma unroll
    for (int j = 0; j < 4; ++j) acc[i][j] = 0.0f;
  int lmm = tid >> 2, lkq = (tid & 3) * 4;
  int lkk = tid >> 4, lnq = (tid & 15) * 4;
  float4 av = *(const float4*)&F[(size_t)(m0 + lmm) * 1024 + lkq];
  float4 bv = *(const float4*)&W[(size_t)lkk * 512 + n0 + lnq];
  for (int k0 = 0; k0 < 1024; k0 += 16){
    As[lkq + 0][lmm] = av.x; As[lkq + 1][lmm] = av.y;
    As[lkq + 2][lmm] = av.z; As[lkq + 3][lmm] = av.w;
    *(float4*)&Bs[lkk][lnq] = bv;
    __syncthreads();
    if (k0 + 16 < 1024){
      av = *(const float4*)&F[(size_t)(m0 + lmm) * 1024 + (k0 + 16) + lkq];
      bv = *(const float4*)&W[(size_t)((k0 + 16) + lkk) * 512 + n0 + lnq];
    }
    #pragma unroll
    for (int kk = 0; kk < 16; ++kk){
      float4 a4 = *(const float4*)&As[kk][ty * 4];
      float4 b4 = *(const float4*)&Bs[kk][tx * 4];
      float a[4] = {a4.x, a4.y, a4.z, a4.w};
      float bb[4] = {b4.x, b4.y, b4.z, b4.w};
      #pragma unroll
      for (int i = 0; i < 4; ++i)
        #pragma unroll
        for (int j = 0; j < 4; ++j) acc[i][j] += a[i] * bb[j];
    }
    __syncthreads();
  }
  float4 bq = *(const float4*)&bias[n0 + tx * 4];
  float bvs[4] = {bq.x, bq.y, bq.z, bq.w};
  float cs[4] = {0,0,0,0}, cq[4] = {0,0,0,0};
  #pragma unroll
  for (int i = 0; i < 4; ++i){
    float v[4];
    #pragma unroll
    for (int j = 0; j < 4; ++j){
      v[j] = mishf(acc[i][j] + bvs[j]);
      cs[j] += v[j]; cq[j] += v[j] * v[j];
    }
    float4 o = make_float4(v[0], v[1], v[2], v[3]);
    *(float4*)&out[(size_t)(m0 + ty * 4 + i) * 512 + n0 + tx * 4] = o;
  }
  #pragma unroll
  for (int j = 0; j < 4; ++j){
    float v = cs[j], w = cq[j];
    v += __shfl_xor(v, 16); w += __shfl_xor(w, 16);
    v += __shfl_xor(v, 32); w += __shfl_xor(w, 32);
    if ((tid & 63) < 16){
      atomicAdd(&csum[tx * 4 + j], v);
      atomicAdd(&csq[tx * 4 + j], w);
    }
  }
  __syncthreads();
  if (tid < 64){
    atomicAdd(&s3[n0 + tid], csum[tid]);
    atomicAdd(&q3[n0 + tid], csq[tid]);
  }
}

// ---------------- mr layer 2 ----------------
__global__ __launch_bounds__(256) void k_mr2(const float* __restrict__ Ain, const float* __restrict__ W,
                                             const float* __restrict__ bias,
                                             const float* __restrict__ s3, const float* __restrict__ q3,
                                             const float* __restrict__ g0, const float* __restrict__ be0,
                                             float* __restrict__ out, float* __restrict__ s4, float* __restrict__ q4){
  __shared__ float As[16][68];
  __shared__ float Bs[16][68];
  __shared__ float A3l[512], C3l[512];
  __shared__ float csum[64], csq[64];
  int tid = threadIdx.x;
  for (int kk = tid; kk < 512; kk += 256){
    const float invR = 1.0f / 4096.0f;
    float mu  = s3[kk] * invR;
    float var = q3[kk] * invR - mu * mu;
    float A = g0[kk] * rsqrtf(var + 1e-3f);
    A3l[kk] = A; C3l[kk] = be0[kk] - mu * A;
  }
  if (tid < 64){ csum[tid] = 0.0f; csq[tid] = 0.0f; }
  __syncthreads();
  int m0 = blockIdx.x * 64;
  int tx = tid & 15, ty = tid >> 4;
  float acc[4][4];
  #pragma unroll
  for (int i = 0; i < 4; ++i)
    #pragma unroll
    for (int j = 0; j < 4; ++j) acc[i][j] = 0.0f;
  int lmm = tid >> 2, lkq = (tid & 3) * 4;
  int lkk = tid >> 4, lnq = (tid & 15) * 4;
  float4 av = *(const float4*)&Ain[(size_t)(m0 + lmm) * 512 + lkq];
  float4 bv = *(const float4*)&W[(size_t)lkk * 64 + lnq];
  for (int k0 = 0; k0 < 512; k0 += 16){
    As[lkq + 0][lmm] = av.x * A3l[k0 + lkq + 0] + C3l[k0 + lkq + 0];
    As[lkq + 1][lmm] = av.y * A3l[k0 + lkq + 1] + C3l[k0 + lkq + 1];
    As[lkq + 2][lmm] = av.z * A3l[k0 + lkq + 2] + C3l[k0 + lkq + 2];
    As[lkq + 3][lmm] = av.w * A3l[k0 + lkq + 3] + C3l[k0 + lkq + 3];
    *(float4*)&Bs[lkk][lnq] = bv;
    __syncthreads();
    if (k0 + 16 < 512){
      av = *(const float4*)&Ain[(size_t)(m0 + lmm) * 512 + (k0 + 16) + lkq];
      bv = *(const float4*)&W[(size_t)((k0 + 16) + lkk) * 64 + lnq];
    }
    #pragma unroll
    for (int kk = 0; kk < 16; ++kk){
      float4 a4 = *(const float4*)&As[kk][ty * 4];
      float4 b4 = *(const float4*)&Bs[kk][tx * 4];
      float a[4] = {a4.x, a4.y, a4.z, a4.w};
      float bb[4] = {b4.x, b4.y, b4.z, b4.w};
      #pragma unroll
      for (int i = 0; i < 4; ++i)
        #pragma unroll
        for (int j = 0; j < 4; ++j) acc[i][j] += a[i] * bb[j];
    }
    __syncthreads();
  }
  float4 bq = *(const float4*)&bias[tx * 4];
  float bvs[4] = {bq.x, bq.y, bq.z, bq.w};
  float cs[4] = {0,0,0,0}, cq[4] = {0,0,0,0};
  #pragma unroll
  for (int i = 0; i < 4; ++i){
    float v[4];
    #pragma unroll
    for (int j = 0; j < 4; ++j){
      v[j] = mishf(acc[i][j] + bvs[j]);
      cs[j] += v[j]; cq[j] += v[j] * v[j];
    }
    float4 o = make_float4(v[0], v[1], v[2], v[3]);
    *(float4*)&out[(size_t)(m0 + ty * 4 + i) * 64 + tx * 4] = o;
  }
  #pragma unroll
  for (int j = 0; j < 4; ++j){
    float v = cs[j], w = cq[j];
    v += __shfl_xor(v, 16); w += __shfl_xor(w, 16);
    v += __shfl_xor(v, 32); w += __shfl_xor(w, 32);
    if ((tid & 63) < 16){
      atomicAdd(&csum[tx * 4 + j], v);
      atomicAdd(&csq[tx * 4 + j], w);
    }
  }
  __syncthreads();
  if (tid < 64){
    atomicAdd(&s4[tid], csum[tid]);
    atomicAdd(&q4[tid], csq[tid]);
  }
}

// ---------------- final BN -> output ----------------
__global__ __launch_bounds__(256) void k_out(const float* __restrict__ pre,
                                             const float* __restrict__ s4, const float* __restrict__ q4,
                                             const float* __restrict__ g1, const float* __restrict__ be1,
                                             float* __restrict__ outp){
  int e = blockIdx.x * 256 + threadIdx.x;
  int c = e & 63;
  const float invR = 1.0f / 4096.0f;
  float mu  = s4[c] * invR;
  float var = q4[c] * invR - mu * mu;
  float A = g1[c] * rsqrtf(var + 1e-3f);
  outp[e] = pre[e] * A + (be1[c] - mu * A);
}

// ---------------- launcher ----------------
extern "C" void kernel_launch(void* const* d_in, const int* in_sizes, int n_in,
                              void* d_out, int out_size, void* d_ws, size_t ws_size,
                              hipStream_t stream){
  (void)in_sizes; (void)n_in; (void)out_size;
  const float* x    = (const float*)d_in[0];
  const float* xyz  = (const float*)d_in[1];
  const float* fpts = (const float*)d_in[2];
  const float* fpw  = (const float*)d_in[3];
  const float* m1w0 = (const float*)d_in[4];
  const float* m1b0 = (const float*)d_in[5];
  const float* m1g0 = (const float*)d_in[6];
  const float* m1be0= (const float*)d_in[7];
  const float* m1w1 = (const float*)d_in[8];
  const float* m1b1 = (const float*)d_in[9];
  const float* m1g1 = (const float*)d_in[10];
  const float* m1be1= (const float*)d_in[11];
  const float* m1w2 = (const float*)d_in[12];
  const float* m1b2 = (const float*)d_in[13];
  const float* m1g2 = (const float*)d_in[14];
  const float* m1be2= (const float*)d_in[15];
  const float* m2w0 = (const float*)d_in[16];
  const float* m2b0 = (const float*)d_in[17];
  const float* m2g0 = (const float*)d_in[18];
  const float* m2be0= (const float*)d_in[19];
  const float* m2w1 = (const float*)d_in[20];
  const float* m2b1 = (const float*)d_in[21];
  const float* m2g1 = (const float*)d_in[22];
  const float* m2be1= (const float*)d_in[23];
  const float* mrw0 = (const float*)d_in[24];
  const float* mrb0 = (const float*)d_in[25];
  const float* mrg0 = (const float*)d_in[26];
  const float* mrbe0= (const float*)d_in[27];
  const float* mrw1 = (const float*)d_in[28];
  const float* mrb1 = (const float*)d_in[29];
  const float* mrg1 = (const float*)d_in[30];
  const float* mrbe1= (const float*)d_in[31];

  float* wsf = (float*)d_ws;
  float* s0 = wsf + 0;     float* q0 = wsf + 512;
  float* s1 = wsf + 1024;  float* q1 = wsf + 1536;
  float* s2 = wsf + 2048;  float* q2 = wsf + 2064;
  float* s3 = wsf + 2080;  float* q3 = wsf + 2592;
  float* s4 = wsf + 3104;  float* q4 = wsf + 3168;
  int*   idxp = (int*)(wsf + 4096);        // 65536 ints -> ends 69632
  double* sqd = (double*)(wsf + 69632);    // 4096 f64 = 8192 floats -> ends 77824
  float* wact0= wsf + 332032;              // 32*512 pre-activation accumulator
  float* wfin = wsf + 348416;              // 32*16
  float* act2 = wsf + 348928;              // 2098176
  float* fbuf = wsf + 2447104;             // 4096*1024 (hosts sib/fjt early)
  float* sib  = fbuf;                      // 65568*32
  float* fjt  = fbuf + 2098176;            // 1024
  float* mact = wsf + 6641408;             // 4096*512
  float* mact2= wsf + 8738560;             // 4096*64  (ends 9000704 floats = 36 MB)

  size_t need = 9000704ULL * 4 + (size_t)RROWS * 32 * 2;
  bool fast = (ws_size >= need);
  ushort_t* a1b = fast ? (ushort_t*)(wsf + 9000704) : nullptr;   // col-major [32][RROWS] bf16

  hipMemsetAsync(d_ws, 0, 4096 * sizeof(float), stream);
  hipMemsetAsync(wact0, 0, 16384 * sizeof(float), stream);

  k_sq<<<16, 256, 0, stream>>>(x, sqd);
  k_topk<<<1024, 256, 0, stream>>>(x, sqd, idxp);
  k_prep<<<257, 256, 0, stream>>>(xyz, fpts, idxp, m1w0, m1b0, sib, fjt);
  k_m1_p1<<<1025, 256, 0, stream>>>(sib, fjt, s0, q0);
  k_m1_p2<<<8196, 256, 0, stream>>>(sib, fjt, m1w1, m1b1, m1g0, m1be0, s0, q0, s1, q1, a1b);
  if (fast){
    k_m1_p3s<<<4098, 256, 0, stream>>>(a1b, m1w2, m1b2, m1g1, m1be1, s1, q1, act2, s2, q2);
  } else {
    k_m1_p3f<<<8196, 256, 0, stream>>>(sib, fjt, m1w1, m1b1, m1g0, m1be0, m1g1, m1be1,
                                       m1w2, m1b2, s0, q0, s1, q1, act2, s2, q2);
  }
  k_wmlp1<<<dim3(32, 8), 512, 0, stream>>>(fpw, m2w0, wact0);
  k_wmlp2<<<1, 512, 0, stream>>>(wact0, m2b0, m2w1, m2b1, m2g0, m2be0, m2g1, m2be1, wfin);
  k_agg<<<4096, 256, 0, stream>>>(act2, wfin, x, idxp, s2, q2, m1g2, m1be2, fbuf);
  k_mr1<<<dim3(8, 64), 256, 0, stream>>>(fbuf, mrw0, mrb0, mact, s3, q3);
  k_mr2<<<64, 256, 0, stream>>>(mact, mrw1, mrb1, s3, q3, mrg0, mrbe0, mact2, s4, q4);
  k_out<<<1024, 256, 0, stream>>>(mact2, s4, q4, mrg1, mrbe1, (float*)d_out);
}

// Round 12
// 535.520 us; speedup vs baseline: 1.0758x; 1.0758x over previous
//
#include <hip/hip_runtime.h>
#include <math.h>

// ---------------- constants ----------------
#define BB    8
#define NN    512
#define CIN   64
#define MAXN  16
#define NF    32
#define MID   16
#define BN_   4096        // B*N
#define MSL   65536       // B*N*MAXN
#define MTOT  65568       // MSL + NF
#define RROWS 2098176     // MTOT*NF  (= 8196*256 = 4098*512)
#define P2STR 40          // LDS row stride in ushorts (80 B, 16B-aligned, conflict-free)

typedef unsigned short ushort_t;
typedef __attribute__((ext_vector_type(8))) short bf16x8;
typedef __attribute__((ext_vector_type(4))) float f32x4;

// ---------------- helpers ----------------
__device__ __forceinline__ float mishf(float x){
  float t  = __expf(x);
  float u  = 1.0f + t;
  float u2 = u * u;
  float r  = x * (u2 - 1.0f) * __builtin_amdgcn_rcpf(u2 + 1.0f);
  return (x > 15.0f) ? x : r;
}

__device__ __forceinline__ ushort_t f2bf(float f){
  unsigned u = __float_as_uint(f);
  unsigned r = (u + 0x7FFFu + ((u >> 16) & 1u)) >> 16;   // RNE
  return (ushort_t)r;
}

__device__ __forceinline__ unsigned rotl32(unsigned v, unsigned s){
  return (v << s) | (v >> (32u - s));
}

// threefry2x32(key=(0,42), x=(0,0)) -> bits = out0 ^ out1  [verified: round-3 pass]
__device__ __forceinline__ float jax_uniform42(){
  unsigned ks[3];
  ks[0] = 0u; ks[1] = 42u; ks[2] = 0x1BD11BDAu ^ 0u ^ 42u;
  const unsigned rot[8] = {13u,15u,26u,6u,17u,29u,16u,24u};
  unsigned x0 = ks[0];
  unsigned x1 = ks[1];
  #pragma unroll
  for (int blk = 0; blk < 5; ++blk){
    #pragma unroll
    for (int r = 0; r < 4; ++r){
      x0 += x1;
      x1 = rotl32(x1, rot[(blk & 1) * 4 + r]);
      x1 ^= x0;
    }
    x0 += ks[(blk + 1) % 3];
    x1 += ks[(blk + 2) % 3] + (unsigned)(blk + 1);
  }
  unsigned w = x0 ^ x1;
  return __uint_as_float((w >> 9) | 0x3f800000u) - 1.0f;
}

// ---------------- k_sq: sqd[r] = sum_c x[r][c]^2 in f64 ----------------
__global__ __launch_bounds__(256) void k_sq(const float* __restrict__ x, double* __restrict__ sqd){
  int r = blockIdx.x * 256 + threadIdx.x;
  const float4* p = (const float4*)(x + (size_t)r * 64);
  double a0 = 0.0, a1 = 0.0, a2 = 0.0, a3 = 0.0;
  #pragma unroll
  for (int k = 0; k < 16; k += 4){
    float4 v0 = p[k], v1 = p[k+1], v2 = p[k+2], v3 = p[k+3];
    a0 += (double)v0.x*v0.x + (double)v0.y*v0.y + (double)v0.z*v0.z + (double)v0.w*v0.w;
    a1 += (double)v1.x*v1.x + (double)v1.y*v1.y + (double)v1.z*v1.z + (double)v1.w*v1.w;
    a2 += (double)v2.x*v2.x + (double)v2.y*v2.y + (double)v2.z*v2.z + (double)v2.w*v2.w;
    a3 += (double)v3.x*v3.x + (double)v3.y*v3.y + (double)v3.z*v3.z + (double)v3.w*v3.w;
  }
  sqd[r] = (a0 + a1) + (a2 + a3);
}

// ---------------- kernel 1: feature-space kNN (top-16, f64) ----------------
// LDS-tiled: candidate tiles staged with coalesced float4 loads (the R11 per-lane
// row scatter cost ~64 L1 transactions per vmem instr -> 55us TA-bound). Compute
// reads candidates from LDS (stride-65 rows: 2-way aliasing = free). f64 chain
// structure identical to R11 -> same idxp.
__global__ __launch_bounds__(256) void k_topk(const float* __restrict__ x, const double* __restrict__ sqd,
                                              int* __restrict__ idxp){
  __shared__ float ct[128 * 65];      // 33280 B candidate tile, row stride 65
  __shared__ float xnl[4][64];
  int tid  = threadIdx.x;
  int lane = tid & 63;
  int wid  = tid >> 6;
  int g = blockIdx.x * 4 + wid;
  int b = g >> 9;
  const float* xb = x + (size_t)b * (NN * CIN);
  {
    int w = tid >> 6, c = tid & 63;
    int nq = (blockIdx.x * 4 + w) & 511;
    xnl[w][c] = xb[nq * 64 + c];
  }
  double sqn = sqd[g];

  double dst[8];
  #pragma unroll 1
  for (int tile = 0; tile < 4; ++tile){
    __syncthreads();                 // ct safe to overwrite (and xnl visible on tile 0)
    #pragma unroll
    for (int u = 0; u < 8; ++u){
      int idx = u * 256 + tid;
      int row = idx >> 4, q = idx & 15;
      float4 v = *(const float4*)&xb[(size_t)(tile * 128 + row) * 64 + q * 4];
      float* d = &ct[row * 65 + q * 4];
      d[0] = v.x; d[1] = v.y; d[2] = v.z; d[3] = v.w;
    }
    __syncthreads();
    double a[2][4];
    #pragma unroll
    for (int s = 0; s < 2; ++s)
      #pragma unroll
      for (int i = 0; i < 4; ++i) a[s][i] = 0.0;
    #pragma unroll
    for (int k = 0; k < 16; ++k){
      float4 qv = *(const float4*)&xnl[wid][k * 4];   // wave-uniform broadcast
      double q0 = (double)qv.x, q1 = (double)qv.y, q2 = (double)qv.z, q3 = (double)qv.w;
      #pragma unroll
      for (int s = 0; s < 2; ++s){
        const float* rp = &ct[(lane + 64 * s) * 65 + k * 4];
        a[s][0] += q0 * (double)rp[0];
        a[s][1] += q1 * (double)rp[1];
        a[s][2] += q2 * (double)rp[2];
        a[s][3] += q3 * (double)rp[3];
      }
    }
    #pragma unroll
    for (int s = 0; s < 2; ++s){
      int m = tile * 128 + 64 * s + lane;
      dst[tile * 2 + s] = sqn + sqd[(b << 9) + m] - 2.0 * ((a[s][0] + a[s][1]) + (a[s][2] + a[s][3]));
    }
  }

  // selection: slot j -> m = (j>>1)*128 + (j&1)*64 + lane
  for (int it = 0; it < 16; ++it){
    double bd = 1.0e300; int bi = 0x7FFFFFFF;
    #pragma unroll
    for (int j = 0; j < 8; ++j){
      int m = ((j >> 1) << 7) + ((j & 1) << 6) + lane;
      if (dst[j] < bd){ bd = dst[j]; bi = m; }
    }
    #pragma unroll
    for (int off = 1; off < 64; off <<= 1){
      double od = __shfl_xor(bd, off);
      int    oi = __shfl_xor(bi, off);
      if (od < bd || (od == bd && oi < bi)){ bd = od; bi = oi; }
    }
    if (lane == 0) idxp[g * 16 + it] = bi;
    if (lane == (bi & 63)){
      int slot = ((bi >> 7) << 1) | ((bi >> 6) & 1);
      #pragma unroll
      for (int j = 0; j < 8; ++j) if (j == slot) dst[j] = 1.0e300;
    }
  }
}

// ---------------- k_prep (fused build_sl + proj): sib[i][c], fjt[c][j] ----------------
__global__ __launch_bounds__(256) void k_prep(const float* __restrict__ xyz,
                                              const float* __restrict__ fpts,
                                              const int* __restrict__ idxp,
                                              const float* __restrict__ w0, const float* __restrict__ b0,
                                              float* __restrict__ sib, float* __restrict__ fjt){
  __shared__ float w0l[96], b0l[32];
  int tid = threadIdx.x;
  if (tid < 96) w0l[tid] = w0[tid];
  else if (tid < 128) b0l[tid - 96] = b0[tid - 96];
  __syncthreads();
  int i = blockIdx.x * 256 + tid;
  if (i >= MTOT) return;
  float vx, vy, vz;
  if (i < MSL){
    int bn = i >> 4, m = i & 15, b = bn >> 9;
    int i0 = idxp[bn * 16];
    int im = idxp[bn * 16 + m];
    const float* xz = xyz + (size_t)b * (NN * 3);
    vx = xz[im * 3 + 0] - xz[i0 * 3 + 0];
    vy = xz[im * 3 + 1] - xz[i0 * 3 + 1];
    vz = xz[im * 3 + 2] - xz[i0 * 3 + 2];
  } else {
    int j = i - MSL;
    float u   = jax_uniform42();
    float ang = (u * 2.0f) * 3.14159274f;
    float c = cosf(ang), s = sinf(ang);
    float fx = fpts[j * 3 + 0], fy = fpts[j * 3 + 1], fz = fpts[j * 3 + 2];
    vx = fx * c - fz * s;
    vy = fy;
    vz = fx * s + fz * c;
  }
  float si[32];
  #pragma unroll
  for (int c = 0; c < 32; ++c)
    si[c] = vx * w0l[c] + vy * w0l[32 + c] + vz * w0l[64 + c];
  float* dst = sib + (size_t)i * 32;
  #pragma unroll
  for (int cq = 0; cq < 8; ++cq){
    float4 o = make_float4(si[cq*4+0] + b0l[cq*4+0], si[cq*4+1] + b0l[cq*4+1],
                           si[cq*4+2] + b0l[cq*4+2], si[cq*4+3] + b0l[cq*4+3]);
    *(float4*)&dst[cq*4] = o;
  }
  if (i >= MSL){
    int j = i - MSL;
    #pragma unroll
    for (int c = 0; c < 32; ++c) fjt[c * 32 + j] = si[c];
  }
}

// ---------------- m1 pass 1: stats of mish(L0) ----------------
__global__ __launch_bounds__(256) void k_m1_p1(const float* __restrict__ sib, const float* __restrict__ fjt,
                                               float* __restrict__ s0g, float* __restrict__ q0g){
  __shared__ float fjlt[1024];           // [j][c]
  __shared__ float red[8][32], redq[8][32];
  int tid = threadIdx.x;
  for (int t = tid; t < 1024; t += 256) fjlt[t] = fjt[(t & 31) * 32 + (t >> 5)];
  __syncthreads();
  int c = tid & 31, s = tid >> 5;
  float as = 0.0f, aq = 0.0f;
  size_t base = (size_t)blockIdx.x * 2048;
  #pragma unroll 4
  for (int t = 0; t < 256; ++t){
    size_t r = base + (size_t)t * 8 + s;
    if (r < (size_t)RROWS){
      int i = (int)(r >> 5), j = (int)(r & 31);
      float m = mishf(sib[(size_t)i * 32 + c] - fjlt[j * 32 + c]);
      as += m; aq += m * m;
    }
  }
  red[s][c] = as; redq[s][c] = aq;
  __syncthreads();
  if (tid < 32){
    float ts = 0.0f, tq = 0.0f;
    #pragma unroll
    for (int ss = 0; ss < 8; ++ss){ ts += red[ss][tid]; tq += redq[ss][tid]; }
    int bank = (blockIdx.x & 15) * 32 + tid;
    atomicAdd(&s0g[bank], ts);
    atomicAdd(&q0g[bank], tq);
  }
}

// ---------------- m1 pass 2: bf16 MFMA GEMM (BN0 folded into weights) -> stats + a1b col-major ----------------
__global__ __launch_bounds__(256, 6) void k_m1_p2(const float* __restrict__ sib, const float* __restrict__ fjt,
                                               const float* __restrict__ w1g, const float* __restrict__ b1g,
                                               const float* __restrict__ g0, const float* __restrict__ be0,
                                               const float* __restrict__ s0g, const float* __restrict__ q0g,
                                               float* __restrict__ s1g, float* __restrict__ q1g,
                                               ushort_t* __restrict__ a1b){
  __shared__ __align__(16) ushort_t a0s[256 * P2STR];    // 20480 B, raw mish(a0) in bf16
  __shared__ __align__(16) float uni[1024];              // fjl (staging) then wts bf16 [c][k]
  __shared__ float A0l[32], C0l[32], biasX[32], satm[32], qatm[32];
  ushort_t* wts = (ushort_t*)uni;
  int tid = threadIdx.x;
  // phase 1: fjl + BN0 coefficients
  for (int t = tid; t < 1024; t += 256) uni[t] = fjt[t];
  if (tid < 32){
    float s = 0.0f, q = 0.0f;
    #pragma unroll
    for (int b = 0; b < 16; ++b){ s += s0g[b * 32 + tid]; q += q0g[b * 32 + tid]; }
    const float invR = 1.0f / (float)RROWS;
    float mu = s * invR, var = q * invR - mu * mu;
    float A = g0[tid] * rsqrtf(var + 1e-3f);
    A0l[tid] = A; C0l[tid] = be0[tid] - mu * A;
    satm[tid] = 0.0f; qatm[tid] = 0.0f;
  }
  __syncthreads();
  // phase 2: staging (raw mish -> bf16 LDS) + folded bias
  {
    int r = blockIdx.x * 256 + tid;
    int i = r >> 5, j = r & 31;
    const float* sr = sib + (size_t)i * 32;
    ushort_t* dst = &a0s[tid * P2STR];
    #pragma unroll
    for (int cq = 0; cq < 4; ++cq){
      float4 sa = *(const float4*)&sr[cq * 8];
      float4 sb = *(const float4*)&sr[cq * 8 + 4];
      float m0 = mishf(sa.x - uni[(cq*8+0)*32 + j]);
      float m1 = mishf(sa.y - uni[(cq*8+1)*32 + j]);
      float m2 = mishf(sa.z - uni[(cq*8+2)*32 + j]);
      float m3 = mishf(sa.w - uni[(cq*8+3)*32 + j]);
      float m4 = mishf(sb.x - uni[(cq*8+4)*32 + j]);
      float m5 = mishf(sb.y - uni[(cq*8+5)*32 + j]);
      float m6 = mishf(sb.z - uni[(cq*8+6)*32 + j]);
      float m7 = mishf(sb.w - uni[(cq*8+7)*32 + j]);
      uint4 pk;
      pk.x = (unsigned)f2bf(m0) | ((unsigned)f2bf(m1) << 16);
      pk.y = (unsigned)f2bf(m2) | ((unsigned)f2bf(m3) << 16);
      pk.z = (unsigned)f2bf(m4) | ((unsigned)f2bf(m5) << 16);
      pk.w = (unsigned)f2bf(m6) | ((unsigned)f2bf(m7) << 16);
      *(uint4*)&dst[cq * 8] = pk;
    }
  }
  if (tid < 32){
    float acc = b1g[tid];
    #pragma unroll
    for (int k = 0; k < 32; ++k) acc += C0l[k] * w1g[k * 32 + tid];
    biasX[tid] = acc;
  }
  __syncthreads();
  // phase 3: wts[c][k] = bf16(w1[k][c] * A0[k])   (overwrites fjl area)
  for (int t = tid; t < 1024; t += 256){
    int k = t >> 5, c = t & 31;
    wts[c * P2STR + k] = f2bf(w1g[t] * A0l[k]);
  }
  __syncthreads();
  // phase 4: MFMA. wave w handles m-tiles w*4..w*4+3, n-tiles 0,1
  int lane = tid & 63, w = tid >> 6;
  int ln15 = lane & 15, quad = lane >> 4;
  f32x4 zero = {0.0f, 0.0f, 0.0f, 0.0f};
  bf16x8 bfr0 = *(bf16x8*)&wts[(ln15) * P2STR + quad * 8];
  bf16x8 bfr1 = *(bf16x8*)&wts[(16 + ln15) * P2STR + quad * 8];
  f32x4 acc[4][2];
  #pragma unroll
  for (int i2 = 0; i2 < 4; ++i2){
    int row = (w * 4 + i2) * 16 + ln15;
    bf16x8 af = *(bf16x8*)&a0s[row * P2STR + quad * 8];
    acc[i2][0] = __builtin_amdgcn_mfma_f32_16x16x32_bf16(af, bfr0, zero, 0, 0, 0);
    acc[i2][1] = __builtin_amdgcn_mfma_f32_16x16x32_bf16(af, bfr1, zero, 0, 0, 0);
  }
  // epilogue: mish + col stats + bf16 col-major store (D: col=lane&15, row=quad*4+reg)
  float cs[2] = {0.0f, 0.0f}, cq2[2] = {0.0f, 0.0f};
  size_t rowbase = (size_t)blockIdx.x * 256 + w * 64 + quad * 4;
  #pragma unroll
  for (int nt = 0; nt < 2; ++nt){
    int col = nt * 16 + ln15;
    float bx = biasX[col];
    size_t colbase = (size_t)col * RROWS;
    #pragma unroll
    for (int i2 = 0; i2 < 4; ++i2){
      f32x4 a = acc[i2][nt];
      float m0 = mishf(a[0] + bx);
      float m1 = mishf(a[1] + bx);
      float m2 = mishf(a[2] + bx);
      float m3 = mishf(a[3] + bx);
      cs[nt]  += m0 + m1 + m2 + m3;
      cq2[nt] += m0*m0 + m1*m1 + m2*m2 + m3*m3;
      if (a1b){
        uint2 pk;
        pk.x = (unsigned)f2bf(m0) | ((unsigned)f2bf(m1) << 16);
        pk.y = (unsigned)f2bf(m2) | ((unsigned)f2bf(m3) << 16);
        *(uint2*)&a1b[colbase + rowbase + (size_t)i2 * 16] = pk;
      }
    }
  }
  #pragma unroll
  for (int nt = 0; nt < 2; ++nt){
    float v = cs[nt], u = cq2[nt];
    v += __shfl_xor(v, 16); u += __shfl_xor(u, 16);
    v += __shfl_xor(v, 32); u += __shfl_xor(u, 32);
    if (lane < 16){
      atomicAdd(&satm[nt * 16 + ln15], v);
      atomicAdd(&qatm[nt * 16 + ln15], u);
    }
  }
  __syncthreads();
  if (tid < 32){
    int bank = (blockIdx.x & 15) * 32 + tid;
    atomicAdd(&s1g[bank], satm[tid]);
    atomicAdd(&q1g[bank], qatm[tid]);
  }
}

// ---------------- m1 pass 3 (streaming): a1b col-major, 2 rows/thread ----------------
__global__ __launch_bounds__(256) void k_m1_p3s(const ushort_t* __restrict__ a1b,
                                                const float* __restrict__ w2g, const float* __restrict__ b2g,
                                                const float* __restrict__ g1, const float* __restrict__ be1,
                                                const float* __restrict__ s1g, const float* __restrict__ q1g,
                                                float* __restrict__ act2, float* __restrict__ s2g, float* __restrict__ q2g){
  __shared__ float vvl[32], C1l[32], cb2l[1], r2s[4], r2q[4];
  int tid = threadIdx.x;
  if (tid < 32){
    float s = 0.0f, q = 0.0f;
    #pragma unroll
    for (int b = 0; b < 16; ++b){ s += s1g[b * 32 + tid]; q += q1g[b * 32 + tid]; }
    const float invR = 1.0f / (float)RROWS;
    float mu = s * invR, var = q * invR - mu * mu;
    float A = g1[tid] * rsqrtf(var + 1e-3f);
    C1l[tid] = be1[tid] - mu * A;
    vvl[tid] = A * w2g[tid];
  }
  __syncthreads();
  if (tid == 0){
    float a = b2g[0];
    #pragma unroll
    for (int k = 0; k < 32; ++k) a += C1l[k] * w2g[k];
    cb2l[0] = a;
  }
  __syncthreads();
  size_t r0 = (size_t)blockIdx.x * 512 + (size_t)tid * 2;
  float pre0 = 0.0f, pre1 = 0.0f;
  #pragma unroll
  for (int c = 0; c < 32; ++c){
    unsigned u = *(const unsigned*)&a1b[(size_t)c * RROWS + r0];
    float lo = __uint_as_float(u << 16);
    float hi = __uint_as_float(u & 0xFFFF0000u);
    pre0 += lo * vvl[c];
    pre1 += hi * vvl[c];
  }
  float cb2 = cb2l[0];
  float a20 = mishf(pre0 + cb2);
  float a21 = mishf(pre1 + cb2);
  *(float2*)&act2[r0] = make_float2(a20, a21);
  float ss = a20 + a21, qq = a20*a20 + a21*a21;
  #pragma unroll
  for (int off = 1; off < 64; off <<= 1){ ss += __shfl_xor(ss, off); qq += __shfl_xor(qq, off); }
  int lane = tid & 63, wid = tid >> 6;
  if (lane == 0){ r2s[wid] = ss; r2q[wid] = qq; }
  __syncthreads();
  if (tid == 0){
    atomicAdd(&s2g[blockIdx.x & 15], r2s[0] + r2s[1] + r2s[2] + r2s[3]);
    atomicAdd(&q2g[blockIdx.x & 15], r2q[0] + r2q[1] + r2q[2] + r2q[3]);
  }
}

// ---------------- m1 pass 3 (fallback, recompute) ----------------
__global__ __launch_bounds__(256, 3) void k_m1_p3f(const float* __restrict__ sib, const float* __restrict__ fjt,
                                               const float* __restrict__ w1g, const float* __restrict__ b1g,
                                               const float* __restrict__ g0, const float* __restrict__ be0,
                                               const float* __restrict__ g1, const float* __restrict__ be1,
                                               const float* __restrict__ w2g, const float* __restrict__ b2g,
                                               const float* __restrict__ s0g, const float* __restrict__ q0g,
                                               const float* __restrict__ s1g, const float* __restrict__ q1g,
                                               float* __restrict__ act2, float* __restrict__ s2g, float* __restrict__ q2g){
  __shared__ float fjl[1024];
  __shared__ float w1s[1024];
  __shared__ float A0l[32], C0l[32], A1l[32], C1l[32], biasX[32], vvl[32];
  __shared__ float a0t[32 * 256];
  __shared__ float cb2l[1];
  __shared__ float r2s[4], r2q[4];
  int tid = threadIdx.x;
  const float invR = 1.0f / (float)RROWS;
  for (int t = tid; t < 1024; t += 256) fjl[t] = fjt[t];
  if (tid < 32){
    float s = 0.0f, q = 0.0f;
    #pragma unroll
    for (int b = 0; b < 16; ++b){ s += s0g[b * 32 + tid]; q += q0g[b * 32 + tid]; }
    float mu = s * invR, var = q * invR - mu * mu;
    float A = g0[tid] * rsqrtf(var + 1e-3f);
    A0l[tid] = A; C0l[tid] = be0[tid] - mu * A;
  } else if (tid < 64){
    int c = tid - 32;
    float s = 0.0f, q = 0.0f;
    #pragma unroll
    for (int b = 0; b < 16; ++b){ s += s1g[b * 32 + c]; q += q1g[b * 32 + c]; }
    float mu = s * invR, var = q * invR - mu * mu;
    float A = g1[c] * rsqrtf(var + 1e-3f);
    A1l[c] = A; C1l[c] = be1[c] - mu * A;
  }
  __syncthreads();
  for (int t = tid; t < 1024; t += 256) w1s[t] = w1g[t] * A0l[t >> 5];
  if (tid < 32){
    float acc = b1g[tid];
    #pragma unroll
    for (int k = 0; k < 32; ++k) acc += C0l[k] * w1g[k * 32 + tid];
    biasX[tid] = acc;
  } else if (tid < 96 && tid >= 64){
    int c = tid - 64;
    vvl[c] = A1l[c] * w2g[c];
  } else if (tid == 96){
    float acc = b2g[0];
    #pragma unroll
    for (int k = 0; k < 32; ++k) acc += C1l[k] * w2g[k];
    cb2l[0] = acc;
  }
  {
    int r = blockIdx.x * 256 + tid;
    int i = r >> 5, j = r & 31;
    const float* sr = sib + (size_t)i * 32;
    #pragma unroll
    for (int cq = 0; cq < 8; ++cq){
      float4 sv = *(const float4*)&sr[cq * 4];
      a0t[(cq*4+0)*256 + tid] = mishf(sv.x - fjl[(cq*4+0)*32 + j]);
      a0t[(cq*4+1)*256 + tid] = mishf(sv.y - fjl[(cq*4+1)*32 + j]);
      a0t[(cq*4+2)*256 + tid] = mishf(sv.z - fjl[(cq*4+2)*32 + j]);
      a0t[(cq*4+3)*256 + tid] = mishf(sv.w - fjl[(cq*4+3)*32 + j]);
    }
  }
  __syncthreads();
  int cg = tid & 7, rg = tid >> 3;
  float acc[8][4];
  #pragma unroll
  for (int i2 = 0; i2 < 8; ++i2)
    #pragma unroll
    for (int j2 = 0; j2 < 4; ++j2) acc[i2][j2] = 0.0f;
  #pragma unroll 4
  for (int k = 0; k < 32; ++k){
    float4 w  = *(const float4*)&w1s[k * 32 + cg * 4];
    float4 aA = *(const float4*)&a0t[k * 256 + rg * 8];
    float4 aB = *(const float4*)&a0t[k * 256 + rg * 8 + 4];
    float ar[8] = {aA.x, aA.y, aA.z, aA.w, aB.x, aB.y, aB.z, aB.w};
    float wc[4] = {w.x, w.y, w.z, w.w};
    #pragma unroll
    for (int i2 = 0; i2 < 8; ++i2)
      #pragma unroll
      for (int j2 = 0; j2 < 4; ++j2) acc[i2][j2] += ar[i2] * wc[j2];
  }
  float cb2 = cb2l[0];
  float ss = 0.0f, qq = 0.0f;
  #pragma unroll
  for (int rr = 0; rr < 8; ++rr){
    float part = 0.0f;
    #pragma unroll
    for (int cc = 0; cc < 4; ++cc){
      float m = mishf(acc[rr][cc] + biasX[cg * 4 + cc]);
      part += m * vvl[cg * 4 + cc];
    }
    part += __shfl_xor(part, 1);
    part += __shfl_xor(part, 2);
    part += __shfl_xor(part, 4);
    float a2 = mishf(part + cb2);
    if (cg == 0){
      act2[(size_t)blockIdx.x * 256 + rg * 8 + rr] = a2;
      ss += a2; qq += a2 * a2;
    }
  }
  #pragma unroll
  for (int off = 1; off < 64; off <<= 1){ ss += __shfl_xor(ss, off); qq += __shfl_xor(qq, off); }
  int lane = tid & 63, wid = tid >> 6;
  if (lane == 0){ r2s[wid] = ss; r2q[wid] = qq; }
  __syncthreads();
  if (tid == 0){
    atomicAdd(&s2g[blockIdx.x & 15], r2s[0] + r2s[1] + r2s[2] + r2s[3]);
    atomicAdd(&q2g[blockIdx.x & 15], r2q[0] + r2q[1] + r2q[2] + r2q[3]);
  }
}

// ---------------- m2 MLP layer 1 (K-split) ----------------
__global__ __launch_bounds__(512) void k_wmlp1(const float* __restrict__ fpw, const float* __restrict__ W0,
                                               float* __restrict__ wact0){
  int f = blockIdx.x, kc = blockIdx.y, c = threadIdx.x;
  const float* row = fpw + (size_t)f * 4096 + kc * 512;
  const float* wp  = W0 + (size_t)(kc * 512) * 512 + c;
  float acc = 0.0f;
  #pragma unroll 8
  for (int k = 0; k < 512; ++k) acc += row[k] * wp[(size_t)k * 512];
  atomicAdd(&wact0[f * 512 + c], acc);
}

// ---------------- m2 MLP finish ----------------
__global__ __launch_bounds__(512) void k_wmlp2(const float* __restrict__ wact0, const float* __restrict__ b0,
                                               const float* __restrict__ W1,
                                               const float* __restrict__ b1,
                                               const float* __restrict__ g0, const float* __restrict__ be0,
                                               const float* __restrict__ g1, const float* __restrict__ be1,
                                               float* __restrict__ wfin){
  __shared__ float wl[32 * 512];
  __shared__ float o2l[512], A1l[16], C1l[16];
  int t = threadIdx.x;
  {
    float b0t = b0[t];
    float v[32]; float sum = 0.0f, sq = 0.0f;
    #pragma unroll
    for (int r = 0; r < 32; ++r){
      v[r] = mishf(wact0[r * 512 + t] + b0t);
      sum += v[r]; sq += v[r] * v[r];
    }
    float mu  = sum * (1.0f / 32.0f);
    float var = sq * (1.0f / 32.0f) - mu * mu;
    float A = g0[t] * rsqrtf(var + 1e-3f);
    float C = be0[t] - mu * A;
    #pragma unroll
    for (int r = 0; r < 32; ++r) wl[r * 512 + t] = v[r] * A + C;
  }
  __syncthreads();
  {
    int r = t >> 4, c2 = t & 15;
    float pre = b1[c2];
    for (int k = 0; k < 512; ++k) pre += wl[r * 512 + k] * W1[k * 16 + c2];
    o2l[t] = mishf(pre);
  }
  __syncthreads();
  if (t < 16){
    float sum = 0.0f, sq = 0.0f;
    #pragma unroll
    for (int r = 0; r < 32; ++r){ float v = o2l[r * 16 + t]; sum += v; sq += v * v; }
    float mu  = sum * (1.0f / 32.0f);
    float var = sq * (1.0f / 32.0f) - mu * mu;
    float A = g1[t] * rsqrtf(var + 1e-3f);
    A1l[t] = A; C1l[t] = be1[t] - mu * A;
  }
  __syncthreads();
  wfin[t] = o2l[t] * A1l[t & 15] + C1l[t & 15];
}

// ---------------- aggregation + per-point einsum -> fbuf[4096,1024] ----------------
__global__ __launch_bounds__(256) void k_agg(const float* __restrict__ act2, const float* __restrict__ wfin,
                                             const float* __restrict__ x, const int* __restrict__ idxp,
                                             const float* __restrict__ s2, const float* __restrict__ q2,
                                             const float* __restrict__ g2, const float* __restrict__ be2,
                                             float* __restrict__ fbuf){
  __shared__ float hl[512], wfl[512], wm[256], furl[1024], AC[2];
  int t = threadIdx.x;
  int k = blockIdx.x;
  if (t == 0){
    const float invR = 1.0f / (float)RROWS;
    float ssum = 0.0f, qsum = 0.0f;
    #pragma unroll
    for (int b = 0; b < 16; ++b){ ssum += s2[b]; qsum += q2[b]; }
    float mu  = ssum * invR;
    float var = qsum * invR - mu * mu;
    float A = g2[0] * rsqrtf(var + 1e-3f);
    AC[0] = A; AC[1] = be2[0] - mu * A;
  }
  wfl[t] = wfin[t]; wfl[t + 256] = wfin[t + 256];
  __syncthreads();
  float A2 = AC[0], C2 = AC[1];
  hl[t]       = act2[(size_t)k * 512 + t]       * A2 + C2;
  hl[t + 256] = act2[(size_t)k * 512 + 256 + t] * A2 + C2;
  __syncthreads();
  {
    int m = t >> 4, d = t & 15;
    float acc = 0.0f;
    #pragma unroll
    for (int j = 0; j < 32; ++j) acc += hl[m * 32 + j] * wfl[j * 16 + d];
    wm[t] = acc;
  }
  int b = k >> 9;
  const float* xb = x + (size_t)b * (NN * CIN);
  {
    int c = t & 63;
    #pragma unroll
    for (int it = 0; it < 4; ++it){
      int m = it * 4 + (t >> 6);
      int im = idxp[k * 16 + m];
      furl[m * 64 + c] = xb[im * 64 + c];
    }
  }
  __syncthreads();
  {
    int d = t & 15, c0 = t >> 4;
    #pragma unroll
    for (int q = 0; q < 4; ++q){
      int c = c0 + 16 * q;
      float acc = 0.0f;
      #pragma unroll
      for (int m = 0; m < 16; ++m) acc += furl[m * 64 + c] * wm[m * 16 + d];
      fbuf[(size_t)k * 1024 + t + 256 * q] = acc;
    }
  }
}

// ---------------- mr layer 1 ----------------
__global__ __launch_bounds__(256) void k_mr1(const float* __restrict__ F, const float* __restrict__ W,
                                             const float* __restrict__ bias, float* __restrict__ out,
                                             float* __restrict__ s3, float* __restrict__ q3){
  __shared__ float As[16][68];
  __shared__ float Bs[16][68];
  __shared__ float csum[64], csq[64];
  int tid = threadIdx.x;
  int m0 = blockIdx.y * 64, n0 = blockIdx.x * 64;
  int tx = tid & 15, ty = tid >> 4;
  if (tid < 64){ csum[tid] = 0.0f; csq[tid] = 0.0f; }
  float acc[4][4];
  #pragma unroll
  for (int i = 0; i < 4; ++i)
    #pragma unroll
    for (int j = 0; j < 4; ++j) acc[i][j] = 0.0f;
  int lmm = tid >> 2, lkq = (tid & 3) * 4;
  int lkk = tid >> 4, lnq = (tid & 15) * 4;
  float4 av = *(const float4*)&F[(size_t)(m0 + lmm) * 1024 + lkq];
  float4 bv = *(const float4*)&W[(size_t)lkk * 512 + n0 + lnq];
  for (int k0 = 0; k0 < 1024; k0 += 16){
    As[lkq + 0][lmm] = av.x; As[lkq + 1][lmm] = av.y;
    As[lkq + 2][lmm] = av.z; As[lkq + 3][lmm] = av.w;
    *(float4*)&Bs[lkk][lnq] = bv;
    __syncthreads();
    if (k0 + 16 < 1024){
      av = *(const float4*)&F[(size_t)(m0 + lmm) * 1024 + (k0 + 16) + lkq];
      bv = *(const float4*)&W[(size_t)((k0 + 16) + lkk) * 512 + n0 + lnq];
    }
    #pragma unroll
    for (int kk = 0; kk < 16; ++kk){
      float4 a4 = *(const float4*)&As[kk][ty * 4];
      float4 b4 = *(const float4*)&Bs[kk][tx * 4];
      float a[4] = {a4.x, a4.y, a4.z, a4.w};
      float bb[4] = {b4.x, b4.y, b4.z, b4.w};
      #pragma unroll
      for (int i = 0; i < 4; ++i)
        #pragma unroll
        for (int j = 0; j < 4; ++j) acc[i][j] += a[i] * bb[j];
    }
    __syncthreads();
  }
  float4 bq = *(const float4*)&bias[n0 + tx * 4];
  float bvs[4] = {bq.x, bq.y, bq.z, bq.w};
  float cs[4] = {0,0,0,0}, cq[4] = {0,0,0,0};
  #pragma unroll
  for (int i = 0; i < 4; ++i){
    float v[4];
    #pragma unroll
    for (int j = 0; j < 4; ++j){
      v[j] = mishf(acc[i][j] + bvs[j]);
      cs[j] += v[j]; cq[j] += v[j] * v[j];
    }
    float4 o = make_float4(v[0], v[1], v[2], v[3]);
    *(float4*)&out[(size_t)(m0 + ty * 4 + i) * 512 + n0 + tx * 4] = o;
  }
  #pragma unroll
  for (int j = 0; j < 4; ++j){
    float v = cs[j], w = cq[j];
    v += __shfl_xor(v, 16); w += __shfl_xor(w, 16);
    v += __shfl_xor(v, 32); w += __shfl_xor(w, 32);
    if ((tid & 63) < 16){
      atomicAdd(&csum[tx * 4 + j], v);
      atomicAdd(&csq[tx * 4 + j], w);
    }
  }
  __syncthreads();
  if (tid < 64){
    atomicAdd(&s3[n0 + tid], csum[tid]);
    atomicAdd(&q3[n0 + tid], csq[tid]);
  }
}

// ---------------- mr layer 2 ----------------
__global__ __launch_bounds__(256) void k_mr2(const float* __restrict__ Ain, const float* __restrict__ W,
                                             const float* __restrict__ bias,
                                             const float* __restrict__ s3, const float* __restrict__ q3,
                                             const float* __restrict__ g0, const float* __restrict__ be0,
                                             float* __restrict__ out, float* __restrict__ s4, float* __restrict__ q4){
  __shared__ float As[16][68];
  __shared__ float Bs[16][68];
  __shared__ float A3l[512], C3l[512];
  __shared__ float csum[64], csq[64];
  int tid = threadIdx.x;
  for (int kk = tid; kk < 512; kk += 256){
    const float invR = 1.0f / 4096.0f;
    float mu  = s3[kk] * invR;
    float var = q3[kk] * invR - mu * mu;
    float A = g0[kk] * rsqrtf(var + 1e-3f);
    A3l[kk] = A; C3l[kk] = be0[kk] - mu * A;
  }
  if (tid < 64){ csum[tid] = 0.0f; csq[tid] = 0.0f; }
  __syncthreads();
  int m0 = blockIdx.x * 64;
  int tx = tid & 15, ty = tid >> 4;
  float acc[4][4];
  #pragma unroll
  for (int i = 0; i < 4; ++i)
    #pragma unroll
    for (int j = 0; j < 4; ++j) acc[i][j] = 0.0f;
  int lmm = tid >> 2, lkq = (tid & 3) * 4;
  int lkk = tid >> 4, lnq = (tid & 15) * 4;
  float4 av = *(const float4*)&Ain[(size_t)(m0 + lmm) * 512 + lkq];
  float4 bv = *(const float4*)&W[(size_t)lkk * 64 + lnq];
  for (int k0 = 0; k0 < 512; k0 += 16){
    As[lkq + 0][lmm] = av.x * A3l[k0 + lkq + 0] + C3l[k0 + lkq + 0];
    As[lkq + 1][lmm] = av.y * A3l[k0 + lkq + 1] + C3l[k0 + lkq + 1];
    As[lkq + 2][lmm] = av.z * A3l[k0 + lkq + 2] + C3l[k0 + lkq + 2];
    As[lkq + 3][lmm] = av.w * A3l[k0 + lkq + 3] + C3l[k0 + lkq + 3];
    *(float4*)&Bs[lkk][lnq] = bv;
    __syncthreads();
    if (k0 + 16 < 512){
      av = *(const float4*)&Ain[(size_t)(m0 + lmm) * 512 + (k0 + 16) + lkq];
      bv = *(const float4*)&W[(size_t)((k0 + 16) + lkk) * 64 + lnq];
    }
    #pragma unroll
    for (int kk = 0; kk < 16; ++kk){
      float4 a4 = *(const float4*)&As[kk][ty * 4];
      float4 b4 = *(const float4*)&Bs[kk][tx * 4];
      float a[4] = {a4.x, a4.y, a4.z, a4.w};
      float bb[4] = {b4.x, b4.y, b4.z, b4.w};
      #pragma unroll
      for (int i = 0; i < 4; ++i)
        #pragma unroll
        for (int j = 0; j < 4; ++j) acc[i][j] += a[i] * bb[j];
    }
    __syncthreads();
  }
  float4 bq = *(const float4*)&bias[tx * 4];
  float bvs[4] = {bq.x, bq.y, bq.z, bq.w};
  float cs[4] = {0,0,0,0}, cq[4] = {0,0,0,0};
  #pragma unroll
  for (int i = 0; i < 4; ++i){
    float v[4];
    #pragma unroll
    for (int j = 0; j < 4; ++j){
      v[j] = mishf(acc[i][j] + bvs[j]);
      cs[j] += v[j]; cq[j] += v[j] * v[j];
    }
    float4 o = make_float4(v[0], v[1], v[2], v[3]);
    *(float4*)&out[(size_t)(m0 + ty * 4 + i) * 64 + tx * 4] = o;
  }
  #pragma unroll
  for (int j = 0; j < 4; ++j){
    float v = cs[j], w = cq[j];
    v += __shfl_xor(v, 16); w += __shfl_xor(w, 16);
    v += __shfl_xor(v, 32); w += __shfl_xor(w, 32);
    if ((tid & 63) < 16){
      atomicAdd(&csum[tx * 4 + j], v);
      atomicAdd(&csq[tx * 4 + j], w);
    }
  }
  __syncthreads();
  if (tid < 64){
    atomicAdd(&s4[tid], csum[tid]);
    atomicAdd(&q4[tid], csq[tid]);
  }
}

// ---------------- final BN -> output ----------------
__global__ __launch_bounds__(256) void k_out(const float* __restrict__ pre,
                                             const float* __restrict__ s4, const float* __restrict__ q4,
                                             const float* __restrict__ g1, const float* __restrict__ be1,
                                             float* __restrict__ outp){
  int e = blockIdx.x * 256 + threadIdx.x;
  int c = e & 63;
  const float invR = 1.0f / 4096.0f;
  float mu  = s4[c] * invR;
  float var = q4[c] * invR - mu * mu;
  float A = g1[c] * rsqrtf(var + 1e-3f);
  outp[e] = pre[e] * A + (be1[c] - mu * A);
}

// ---------------- launcher ----------------
extern "C" void kernel_launch(void* const* d_in, const int* in_sizes, int n_in,
                              void* d_out, int out_size, void* d_ws, size_t ws_size,
                              hipStream_t stream){
  (void)in_sizes; (void)n_in; (void)out_size;
  const float* x    = (const float*)d_in[0];
  const float* xyz  = (const float*)d_in[1];
  const float* fpts = (const float*)d_in[2];
  const float* fpw  = (const float*)d_in[3];
  const float* m1w0 = (const float*)d_in[4];
  const float* m1b0 = (const float*)d_in[5];
  const float* m1g0 = (const float*)d_in[6];
  const float* m1be0= (const float*)d_in[7];
  const float* m1w1 = (const float*)d_in[8];
  const float* m1b1 = (const float*)d_in[9];
  const float* m1g1 = (const float*)d_in[10];
  const float* m1be1= (const float*)d_in[11];
  const float* m1w2 = (const float*)d_in[12];
  const float* m1b2 = (const float*)d_in[13];
  const float* m1g2 = (const float*)d_in[14];
  const float* m1be2= (const float*)d_in[15];
  const float* m2w0 = (const float*)d_in[16];
  const float* m2b0 = (const float*)d_in[17];
  const float* m2g0 = (const float*)d_in[18];
  const float* m2be0= (const float*)d_in[19];
  const float* m2w1 = (const float*)d_in[20];
  const float* m2b1 = (const float*)d_in[21];
  const float* m2g1 = (const float*)d_in[22];
  const float* m2be1= (const float*)d_in[23];
  const float* mrw0 = (const float*)d_in[24];
  const float* mrb0 = (const float*)d_in[25];
  const float* mrg0 = (const float*)d_in[26];
  const float* mrbe0= (const float*)d_in[27];
  const float* mrw1 = (const float*)d_in[28];
  const float* mrb1 = (const float*)d_in[29];
  const float* mrg1 = (const float*)d_in[30];
  const float* mrbe1= (const float*)d_in[31];

  float* wsf = (float*)d_ws;
  float* s0 = wsf + 0;     float* q0 = wsf + 512;
  float* s1 = wsf + 1024;  float* q1 = wsf + 1536;
  float* s2 = wsf + 2048;  float* q2 = wsf + 2064;
  float* s3 = wsf + 2080;  float* q3 = wsf + 2592;
  float* s4 = wsf + 3104;  float* q4 = wsf + 3168;
  int*   idxp = (int*)(wsf + 4096);        // 65536 ints -> ends 69632
  double* sqd = (double*)(wsf + 69632);    // 4096 f64 = 8192 floats -> ends 77824
  float* wact0= wsf + 332032;              // 32*512 pre-activation accumulator
  float* wfin = wsf + 348416;              // 32*16
  float* act2 = wsf + 348928;              // 2098176
  float* fbuf = wsf + 2447104;             // 4096*1024 (hosts sib/fjt early)
  float* sib  = fbuf;                      // 65568*32
  float* fjt  = fbuf + 2098176;            // 1024
  float* mact = wsf + 6641408;             // 4096*512
  float* mact2= wsf + 8738560;             // 4096*64  (ends 9000704 floats = 36 MB)

  size_t need = 9000704ULL * 4 + (size_t)RROWS * 32 * 2;
  bool fast = (ws_size >= need);
  ushort_t* a1b = fast ? (ushort_t*)(wsf + 9000704) : nullptr;   // col-major [32][RROWS] bf16

  hipMemsetAsync(d_ws, 0, 4096 * sizeof(float), stream);
  hipMemsetAsync(wact0, 0, 16384 * sizeof(float), stream);

  k_sq<<<16, 256, 0, stream>>>(x, sqd);
  k_topk<<<1024, 256, 0, stream>>>(x, sqd, idxp);
  k_prep<<<257, 256, 0, stream>>>(xyz, fpts, idxp, m1w0, m1b0, sib, fjt);
  k_m1_p1<<<1025, 256, 0, stream>>>(sib, fjt, s0, q0);
  k_m1_p2<<<8196, 256, 0, stream>>>(sib, fjt, m1w1, m1b1, m1g0, m1be0, s0, q0, s1, q1, a1b);
  if (fast){
    k_m1_p3s<<<4098, 256, 0, stream>>>(a1b, m1w2, m1b2, m1g1, m1be1, s1, q1, act2, s2, q2);
  } else {
    k_m1_p3f<<<8196, 256, 0, stream>>>(sib, fjt, m1w1, m1b1, m1g0, m1be0, m1g1, m1be1,
                                       m1w2, m1b2, s0, q0, s1, q1, act2, s2, q2);
  }
  k_wmlp1<<<dim3(32, 8), 512, 0, stream>>>(fpw, m2w0, wact0);
  k_wmlp2<<<1, 512, 0, stream>>>(wact0, m2b0, m2w1, m2b1, m2g0, m2be0, m2g1, m2be1, wfin);
  k_agg<<<4096, 256, 0, stream>>>(act2, wfin, x, idxp, s2, q2, m1g2, m1be2, fbuf);
  k_mr1<<<dim3(8, 64), 256, 0, stream>>>(fbuf, mrw0, mrb0, mact, s3, q3);
  k_mr2<<<64, 256, 0, stream>>>(mact, mrw1, mrb1, s3, q3, mrg0, mrbe0, mact2, s4, q4);
  k_out<<<1024, 256, 0, stream>>>(mact2, s4, q4, mrg1, mrbe1, (float*)d_out);
}

// Round 13
// 503.053 us; speedup vs baseline: 1.1452x; 1.0645x over previous
//
#include <hip/hip_runtime.h>
#include <math.h>

// ---------------- constants ----------------
#define BB    8
#define NN    512
#define CIN   64
#define MAXN  16
#define NF    32
#define MID   16
#define BN_   4096        // B*N
#define MSL   65536       // B*N*MAXN
#define MTOT  65568       // MSL + NF
#define RROWS 2098176     // MTOT*NF  (= 8196*256 = 4098*512)
#define P2STR 40          // LDS row stride in ushorts (80 B, 16B-aligned, conflict-free)
#define AST   72          // mr1 LDS row stride in ushorts (144 B)

typedef unsigned short ushort_t;
typedef __attribute__((ext_vector_type(8))) short bf16x8;
typedef __attribute__((ext_vector_type(4))) float f32x4;

// ---------------- helpers ----------------
__device__ __forceinline__ float mishf(float x){
  float t  = __expf(x);
  float u  = 1.0f + t;
  float u2 = u * u;
  float r  = x * (u2 - 1.0f) * __builtin_amdgcn_rcpf(u2 + 1.0f);
  return (x > 15.0f) ? x : r;
}

__device__ __forceinline__ ushort_t f2bf(float f){
  unsigned u = __float_as_uint(f);
  unsigned r = (u + 0x7FFFu + ((u >> 16) & 1u)) >> 16;   // RNE
  return (ushort_t)r;
}

__device__ __forceinline__ unsigned rotl32(unsigned v, unsigned s){
  return (v << s) | (v >> (32u - s));
}

// threefry2x32(key=(0,42), x=(0,0)) -> bits = out0 ^ out1  [verified: round-3 pass]
__device__ __forceinline__ float jax_uniform42(){
  unsigned ks[3];
  ks[0] = 0u; ks[1] = 42u; ks[2] = 0x1BD11BDAu ^ 0u ^ 42u;
  const unsigned rot[8] = {13u,15u,26u,6u,17u,29u,16u,24u};
  unsigned x0 = ks[0];
  unsigned x1 = ks[1];
  #pragma unroll
  for (int blk = 0; blk < 5; ++blk){
    #pragma unroll
    for (int r = 0; r < 4; ++r){
      x0 += x1;
      x1 = rotl32(x1, rot[(blk & 1) * 4 + r]);
      x1 ^= x0;
    }
    x0 += ks[(blk + 1) % 3];
    x1 += ks[(blk + 2) % 3] + (unsigned)(blk + 1);
  }
  unsigned w = x0 ^ x1;
  return __uint_as_float((w >> 9) | 0x3f800000u) - 1.0f;
}

// ---------------- k_sq: sqd[r] = sum_c x[r][c]^2 in f64 ----------------
__global__ __launch_bounds__(256) void k_sq(const float* __restrict__ x, double* __restrict__ sqd){
  int r = blockIdx.x * 256 + threadIdx.x;
  const float4* p = (const float4*)(x + (size_t)r * 64);
  double a0 = 0.0, a1 = 0.0, a2 = 0.0, a3 = 0.0;
  #pragma unroll
  for (int k = 0; k < 16; k += 4){
    float4 v0 = p[k], v1 = p[k+1], v2 = p[k+2], v3 = p[k+3];
    a0 += (double)v0.x*v0.x + (double)v0.y*v0.y + (double)v0.z*v0.z + (double)v0.w*v0.w;
    a1 += (double)v1.x*v1.x + (double)v1.y*v1.y + (double)v1.z*v1.z + (double)v1.w*v1.w;
    a2 += (double)v2.x*v2.x + (double)v2.y*v2.y + (double)v2.z*v2.z + (double)v2.w*v2.w;
    a3 += (double)v3.x*v3.x + (double)v3.y*v3.y + (double)v3.z*v3.z + (double)v3.w*v3.w;
  }
  sqd[r] = (a0 + a1) + (a2 + a3);
}

// ---------------- kernel 1: feature-space kNN (top-16, f64) ----------------
__global__ __launch_bounds__(256) void k_topk(const float* __restrict__ x, const double* __restrict__ sqd,
                                              int* __restrict__ idxp){
  __shared__ float ct[128 * 65];      // 33280 B candidate tile, row stride 65
  __shared__ float xnl[4][64];
  int tid  = threadIdx.x;
  int lane = tid & 63;
  int wid  = tid >> 6;
  int g = blockIdx.x * 4 + wid;
  int b = g >> 9;
  const float* xb = x + (size_t)b * (NN * CIN);
  {
    int w = tid >> 6, c = tid & 63;
    int nq = (blockIdx.x * 4 + w) & 511;
    xnl[w][c] = xb[nq * 64 + c];
  }
  double sqn = sqd[g];

  double dst[8];
  #pragma unroll 1
  for (int tile = 0; tile < 4; ++tile){
    __syncthreads();
    #pragma unroll
    for (int u = 0; u < 8; ++u){
      int idx = u * 256 + tid;
      int row = idx >> 4, q = idx & 15;
      float4 v = *(const float4*)&xb[(size_t)(tile * 128 + row) * 64 + q * 4];
      float* d = &ct[row * 65 + q * 4];
      d[0] = v.x; d[1] = v.y; d[2] = v.z; d[3] = v.w;
    }
    __syncthreads();
    double a[2][4];
    #pragma unroll
    for (int s = 0; s < 2; ++s)
      #pragma unroll
      for (int i = 0; i < 4; ++i) a[s][i] = 0.0;
    #pragma unroll
    for (int k = 0; k < 16; ++k){
      float4 qv = *(const float4*)&xnl[wid][k * 4];
      double q0 = (double)qv.x, q1 = (double)qv.y, q2 = (double)qv.z, q3 = (double)qv.w;
      #pragma unroll
      for (int s = 0; s < 2; ++s){
        const float* rp = &ct[(lane + 64 * s) * 65 + k * 4];
        a[s][0] += q0 * (double)rp[0];
        a[s][1] += q1 * (double)rp[1];
        a[s][2] += q2 * (double)rp[2];
        a[s][3] += q3 * (double)rp[3];
      }
    }
    #pragma unroll
    for (int s = 0; s < 2; ++s){
      int m = tile * 128 + 64 * s + lane;
      dst[tile * 2 + s] = sqn + sqd[(b << 9) + m] - 2.0 * ((a[s][0] + a[s][1]) + (a[s][2] + a[s][3]));
    }
  }

  for (int it = 0; it < 16; ++it){
    double bd = 1.0e300; int bi = 0x7FFFFFFF;
    #pragma unroll
    for (int j = 0; j < 8; ++j){
      int m = ((j >> 1) << 7) + ((j & 1) << 6) + lane;
      if (dst[j] < bd){ bd = dst[j]; bi = m; }
    }
    #pragma unroll
    for (int off = 1; off < 64; off <<= 1){
      double od = __shfl_xor(bd, off);
      int    oi = __shfl_xor(bi, off);
      if (od < bd || (od == bd && oi < bi)){ bd = od; bi = oi; }
    }
    if (lane == 0) idxp[g * 16 + it] = bi;
    if (lane == (bi & 63)){
      int slot = ((bi >> 7) << 1) | ((bi >> 6) & 1);
      #pragma unroll
      for (int j = 0; j < 8; ++j) if (j == slot) dst[j] = 1.0e300;
    }
  }
}

// ---------------- k_prep (fused build_sl + proj): sib[i][c], fjt[c][j] ----------------
__global__ __launch_bounds__(256) void k_prep(const float* __restrict__ xyz,
                                              const float* __restrict__ fpts,
                                              const int* __restrict__ idxp,
                                              const float* __restrict__ w0, const float* __restrict__ b0,
                                              float* __restrict__ sib, float* __restrict__ fjt){
  __shared__ float w0l[96], b0l[32];
  int tid = threadIdx.x;
  if (tid < 96) w0l[tid] = w0[tid];
  else if (tid < 128) b0l[tid - 96] = b0[tid - 96];
  __syncthreads();
  int i = blockIdx.x * 256 + tid;
  if (i >= MTOT) return;
  float vx, vy, vz;
  if (i < MSL){
    int bn = i >> 4, m = i & 15, b = bn >> 9;
    int i0 = idxp[bn * 16];
    int im = idxp[bn * 16 + m];
    const float* xz = xyz + (size_t)b * (NN * 3);
    vx = xz[im * 3 + 0] - xz[i0 * 3 + 0];
    vy = xz[im * 3 + 1] - xz[i0 * 3 + 1];
    vz = xz[im * 3 + 2] - xz[i0 * 3 + 2];
  } else {
    int j = i - MSL;
    float u   = jax_uniform42();
    float ang = (u * 2.0f) * 3.14159274f;
    float c = cosf(ang), s = sinf(ang);
    float fx = fpts[j * 3 + 0], fy = fpts[j * 3 + 1], fz = fpts[j * 3 + 2];
    vx = fx * c - fz * s;
    vy = fy;
    vz = fx * s + fz * c;
  }
  float si[32];
  #pragma unroll
  for (int c = 0; c < 32; ++c)
    si[c] = vx * w0l[c] + vy * w0l[32 + c] + vz * w0l[64 + c];
  float* dst = sib + (size_t)i * 32;
  #pragma unroll
  for (int cq = 0; cq < 8; ++cq){
    float4 o = make_float4(si[cq*4+0] + b0l[cq*4+0], si[cq*4+1] + b0l[cq*4+1],
                           si[cq*4+2] + b0l[cq*4+2], si[cq*4+3] + b0l[cq*4+3]);
    *(float4*)&dst[cq*4] = o;
  }
  if (i >= MSL){
    int j = i - MSL;
    #pragma unroll
    for (int c = 0; c < 32; ++c) fjt[c * 32 + j] = si[c];
  }
}

// ---------------- m1 pass 1: stats of mish(L0) ----------------
__global__ __launch_bounds__(256) void k_m1_p1(const float* __restrict__ sib, const float* __restrict__ fjt,
                                               float* __restrict__ s0g, float* __restrict__ q0g){
  __shared__ float fjlt[1024];           // [j][c]
  __shared__ float red[8][32], redq[8][32];
  int tid = threadIdx.x;
  for (int t = tid; t < 1024; t += 256) fjlt[t] = fjt[(t & 31) * 32 + (t >> 5)];
  __syncthreads();
  int c = tid & 31, s = tid >> 5;
  float as = 0.0f, aq = 0.0f;
  size_t base = (size_t)blockIdx.x * 2048;
  #pragma unroll 4
  for (int t = 0; t < 256; ++t){
    size_t r = base + (size_t)t * 8 + s;
    if (r < (size_t)RROWS){
      int i = (int)(r >> 5), j = (int)(r & 31);
      float m = mishf(sib[(size_t)i * 32 + c] - fjlt[j * 32 + c]);
      as += m; aq += m * m;
    }
  }
  red[s][c] = as; redq[s][c] = aq;
  __syncthreads();
  if (tid < 32){
    float ts = 0.0f, tq = 0.0f;
    #pragma unroll
    for (int ss = 0; ss < 8; ++ss){ ts += red[ss][tid]; tq += redq[ss][tid]; }
    int bank = (blockIdx.x & 15) * 32 + tid;
    atomicAdd(&s0g[bank], ts);
    atomicAdd(&q0g[bank], tq);
  }
}

// ---------------- m1 pass 2: bf16 MFMA GEMM (BN0 folded into weights) -> stats + a1b col-major ----------------
__global__ __launch_bounds__(256, 6) void k_m1_p2(const float* __restrict__ sib, const float* __restrict__ fjt,
                                               const float* __restrict__ w1g, const float* __restrict__ b1g,
                                               const float* __restrict__ g0, const float* __restrict__ be0,
                                               const float* __restrict__ s0g, const float* __restrict__ q0g,
                                               float* __restrict__ s1g, float* __restrict__ q1g,
                                               ushort_t* __restrict__ a1b){
  __shared__ __align__(16) ushort_t a0s[256 * P2STR];    // 20480 B, raw mish(a0) in bf16
  __shared__ __align__(16) float uni[1024];              // fjl (staging) then wts bf16 [c][k]
  __shared__ float A0l[32], C0l[32], biasX[32], satm[32], qatm[32];
  ushort_t* wts = (ushort_t*)uni;
  int tid = threadIdx.x;
  for (int t = tid; t < 1024; t += 256) uni[t] = fjt[t];
  if (tid < 32){
    float s = 0.0f, q = 0.0f;
    #pragma unroll
    for (int b = 0; b < 16; ++b){ s += s0g[b * 32 + tid]; q += q0g[b * 32 + tid]; }
    const float invR = 1.0f / (float)RROWS;
    float mu = s * invR, var = q * invR - mu * mu;
    float A = g0[tid] * rsqrtf(var + 1e-3f);
    A0l[tid] = A; C0l[tid] = be0[tid] - mu * A;
    satm[tid] = 0.0f; qatm[tid] = 0.0f;
  }
  __syncthreads();
  {
    int r = blockIdx.x * 256 + tid;
    int i = r >> 5, j = r & 31;
    const float* sr = sib + (size_t)i * 32;
    ushort_t* dst = &a0s[tid * P2STR];
    #pragma unroll
    for (int cq = 0; cq < 4; ++cq){
      float4 sa = *(const float4*)&sr[cq * 8];
      float4 sb = *(const float4*)&sr[cq * 8 + 4];
      float m0 = mishf(sa.x - uni[(cq*8+0)*32 + j]);
      float m1 = mishf(sa.y - uni[(cq*8+1)*32 + j]);
      float m2 = mishf(sa.z - uni[(cq*8+2)*32 + j]);
      float m3 = mishf(sa.w - uni[(cq*8+3)*32 + j]);
      float m4 = mishf(sb.x - uni[(cq*8+4)*32 + j]);
      float m5 = mishf(sb.y - uni[(cq*8+5)*32 + j]);
      float m6 = mishf(sb.z - uni[(cq*8+6)*32 + j]);
      float m7 = mishf(sb.w - uni[(cq*8+7)*32 + j]);
      uint4 pk;
      pk.x = (unsigned)f2bf(m0) | ((unsigned)f2bf(m1) << 16);
      pk.y = (unsigned)f2bf(m2) | ((unsigned)f2bf(m3) << 16);
      pk.z = (unsigned)f2bf(m4) | ((unsigned)f2bf(m5) << 16);
      pk.w = (unsigned)f2bf(m6) | ((unsigned)f2bf(m7) << 16);
      *(uint4*)&dst[cq * 8] = pk;
    }
  }
  if (tid < 32){
    float acc = b1g[tid];
    #pragma unroll
    for (int k = 0; k < 32; ++k) acc += C0l[k] * w1g[k * 32 + tid];
    biasX[tid] = acc;
  }
  __syncthreads();
  for (int t = tid; t < 1024; t += 256){
    int k = t >> 5, c = t & 31;
    wts[c * P2STR + k] = f2bf(w1g[t] * A0l[k]);
  }
  __syncthreads();
  int lane = tid & 63, w = tid >> 6;
  int ln15 = lane & 15, quad = lane >> 4;
  f32x4 zero = {0.0f, 0.0f, 0.0f, 0.0f};
  bf16x8 bfr0 = *(bf16x8*)&wts[(ln15) * P2STR + quad * 8];
  bf16x8 bfr1 = *(bf16x8*)&wts[(16 + ln15) * P2STR + quad * 8];
  f32x4 acc[4][2];
  #pragma unroll
  for (int i2 = 0; i2 < 4; ++i2){
    int row = (w * 4 + i2) * 16 + ln15;
    bf16x8 af = *(bf16x8*)&a0s[row * P2STR + quad * 8];
    acc[i2][0] = __builtin_amdgcn_mfma_f32_16x16x32_bf16(af, bfr0, zero, 0, 0, 0);
    acc[i2][1] = __builtin_amdgcn_mfma_f32_16x16x32_bf16(af, bfr1, zero, 0, 0, 0);
  }
  float cs[2] = {0.0f, 0.0f}, cq2[2] = {0.0f, 0.0f};
  size_t rowbase = (size_t)blockIdx.x * 256 + w * 64 + quad * 4;
  #pragma unroll
  for (int nt = 0; nt < 2; ++nt){
    int col = nt * 16 + ln15;
    float bx = biasX[col];
    size_t colbase = (size_t)col * RROWS;
    #pragma unroll
    for (int i2 = 0; i2 < 4; ++i2){
      f32x4 a = acc[i2][nt];
      float m0 = mishf(a[0] + bx);
      float m1 = mishf(a[1] + bx);
      float m2 = mishf(a[2] + bx);
      float m3 = mishf(a[3] + bx);
      cs[nt]  += m0 + m1 + m2 + m3;
      cq2[nt] += m0*m0 + m1*m1 + m2*m2 + m3*m3;
      if (a1b){
        uint2 pk;
        pk.x = (unsigned)f2bf(m0) | ((unsigned)f2bf(m1) << 16);
        pk.y = (unsigned)f2bf(m2) | ((unsigned)f2bf(m3) << 16);
        *(uint2*)&a1b[colbase + rowbase + (size_t)i2 * 16] = pk;
      }
    }
  }
  #pragma unroll
  for (int nt = 0; nt < 2; ++nt){
    float v = cs[nt], u = cq2[nt];
    v += __shfl_xor(v, 16); u += __shfl_xor(u, 16);
    v += __shfl_xor(v, 32); u += __shfl_xor(u, 32);
    if (lane < 16){
      atomicAdd(&satm[nt * 16 + ln15], v);
      atomicAdd(&qatm[nt * 16 + ln15], u);
    }
  }
  __syncthreads();
  if (tid < 32){
    int bank = (blockIdx.x & 15) * 32 + tid;
    atomicAdd(&s1g[bank], satm[tid]);
    atomicAdd(&q1g[bank], qatm[tid]);
  }
}

// ---------------- m1 pass 3 (streaming): a1b col-major, 2 rows/thread ----------------
__global__ __launch_bounds__(256) void k_m1_p3s(const ushort_t* __restrict__ a1b,
                                                const float* __restrict__ w2g, const float* __restrict__ b2g,
                                                const float* __restrict__ g1, const float* __restrict__ be1,
                                                const float* __restrict__ s1g, const float* __restrict__ q1g,
                                                float* __restrict__ act2, float* __restrict__ s2g, float* __restrict__ q2g){
  __shared__ float vvl[32], C1l[32], cb2l[1], r2s[4], r2q[4];
  int tid = threadIdx.x;
  if (tid < 32){
    float s = 0.0f, q = 0.0f;
    #pragma unroll
    for (int b = 0; b < 16; ++b){ s += s1g[b * 32 + tid]; q += q1g[b * 32 + tid]; }
    const float invR = 1.0f / (float)RROWS;
    float mu = s * invR, var = q * invR - mu * mu;
    float A = g1[tid] * rsqrtf(var + 1e-3f);
    C1l[tid] = be1[tid] - mu * A;
    vvl[tid] = A * w2g[tid];
  }
  __syncthreads();
  if (tid == 0){
    float a = b2g[0];
    #pragma unroll
    for (int k = 0; k < 32; ++k) a += C1l[k] * w2g[k];
    cb2l[0] = a;
  }
  __syncthreads();
  size_t r0 = (size_t)blockIdx.x * 512 + (size_t)tid * 2;
  float pre0 = 0.0f, pre1 = 0.0f;
  #pragma unroll
  for (int c = 0; c < 32; ++c){
    unsigned u = *(const unsigned*)&a1b[(size_t)c * RROWS + r0];
    float lo = __uint_as_float(u << 16);
    float hi = __uint_as_float(u & 0xFFFF0000u);
    pre0 += lo * vvl[c];
    pre1 += hi * vvl[c];
  }
  float cb2 = cb2l[0];
  float a20 = mishf(pre0 + cb2);
  float a21 = mishf(pre1 + cb2);
  *(float2*)&act2[r0] = make_float2(a20, a21);
  float ss = a20 + a21, qq = a20*a20 + a21*a21;
  #pragma unroll
  for (int off = 1; off < 64; off <<= 1){ ss += __shfl_xor(ss, off); qq += __shfl_xor(qq, off); }
  int lane = tid & 63, wid = tid >> 6;
  if (lane == 0){ r2s[wid] = ss; r2q[wid] = qq; }
  __syncthreads();
  if (tid == 0){
    atomicAdd(&s2g[blockIdx.x & 15], r2s[0] + r2s[1] + r2s[2] + r2s[3]);
    atomicAdd(&q2g[blockIdx.x & 15], r2q[0] + r2q[1] + r2q[2] + r2q[3]);
  }
}

// ---------------- m1 pass 3 (fallback, recompute) ----------------
__global__ __launch_bounds__(256, 3) void k_m1_p3f(const float* __restrict__ sib, const float* __restrict__ fjt,
                                               const float* __restrict__ w1g, const float* __restrict__ b1g,
                                               const float* __restrict__ g0, const float* __restrict__ be0,
                                               const float* __restrict__ g1, const float* __restrict__ be1,
                                               const float* __restrict__ w2g, const float* __restrict__ b2g,
                                               const float* __restrict__ s0g, const float* __restrict__ q0g,
                                               const float* __restrict__ s1g, const float* __restrict__ q1g,
                                               float* __restrict__ act2, float* __restrict__ s2g, float* __restrict__ q2g){
  __shared__ float fjl[1024];
  __shared__ float w1s[1024];
  __shared__ float A0l[32], C0l[32], A1l[32], C1l[32], biasX[32], vvl[32];
  __shared__ float a0t[32 * 256];
  __shared__ float cb2l[1];
  __shared__ float r2s[4], r2q[4];
  int tid = threadIdx.x;
  const float invR = 1.0f / (float)RROWS;
  for (int t = tid; t < 1024; t += 256) fjl[t] = fjt[t];
  if (tid < 32){
    float s = 0.0f, q = 0.0f;
    #pragma unroll
    for (int b = 0; b < 16; ++b){ s += s0g[b * 32 + tid]; q += q0g[b * 32 + tid]; }
    float mu = s * invR, var = q * invR - mu * mu;
    float A = g0[tid] * rsqrtf(var + 1e-3f);
    A0l[tid] = A; C0l[tid] = be0[tid] - mu * A;
  } else if (tid < 64){
    int c = tid - 32;
    float s = 0.0f, q = 0.0f;
    #pragma unroll
    for (int b = 0; b < 16; ++b){ s += s1g[b * 32 + c]; q += q1g[b * 32 + c]; }
    float mu = s * invR, var = q * invR - mu * mu;
    float A = g1[c] * rsqrtf(var + 1e-3f);
    A1l[c] = A; C1l[c] = be1[c] - mu * A;
  }
  __syncthreads();
  for (int t = tid; t < 1024; t += 256) w1s[t] = w1g[t] * A0l[t >> 5];
  if (tid < 32){
    float acc = b1g[tid];
    #pragma unroll
    for (int k = 0; k < 32; ++k) acc += C0l[k] * w1g[k * 32 + tid];
    biasX[tid] = acc;
  } else if (tid < 96 && tid >= 64){
    int c = tid - 64;
    vvl[c] = A1l[c] * w2g[c];
  } else if (tid == 96){
    float acc = b2g[0];
    #pragma unroll
    for (int k = 0; k < 32; ++k) acc += C1l[k] * w2g[k];
    cb2l[0] = acc;
  }
  {
    int r = blockIdx.x * 256 + tid;
    int i = r >> 5, j = r & 31;
    const float* sr = sib + (size_t)i * 32;
    #pragma unroll
    for (int cq = 0; cq < 8; ++cq){
      float4 sv = *(const float4*)&sr[cq * 4];
      a0t[(cq*4+0)*256 + tid] = mishf(sv.x - fjl[(cq*4+0)*32 + j]);
      a0t[(cq*4+1)*256 + tid] = mishf(sv.y - fjl[(cq*4+1)*32 + j]);
      a0t[(cq*4+2)*256 + tid] = mishf(sv.z - fjl[(cq*4+2)*32 + j]);
      a0t[(cq*4+3)*256 + tid] = mishf(sv.w - fjl[(cq*4+3)*32 + j]);
    }
  }
  __syncthreads();
  int cg = tid & 7, rg = tid >> 3;
  float acc[8][4];
  #pragma unroll
  for (int i2 = 0; i2 < 8; ++i2)
    #pragma unroll
    for (int j2 = 0; j2 < 4; ++j2) acc[i2][j2] = 0.0f;
  #pragma unroll 4
  for (int k = 0; k < 32; ++k){
    float4 w  = *(const float4*)&w1s[k * 32 + cg * 4];
    float4 aA = *(const float4*)&a0t[k * 256 + rg * 8];
    float4 aB = *(const float4*)&a0t[k * 256 + rg * 8 + 4];
    float ar[8] = {aA.x, aA.y, aA.z, aA.w, aB.x, aB.y, aB.z, aB.w};
    float wc[4] = {w.x, w.y, w.z, w.w};
    #pragma unroll
    for (int i2 = 0; i2 < 8; ++i2)
      #pragma unroll
      for (int j2 = 0; j2 < 4; ++j2) acc[i2][j2] += ar[i2] * wc[j2];
  }
  float cb2 = cb2l[0];
  float ss = 0.0f, qq = 0.0f;
  #pragma unroll
  for (int rr = 0; rr < 8; ++rr){
    float part = 0.0f;
    #pragma unroll
    for (int cc = 0; cc < 4; ++cc){
      float m = mishf(acc[rr][cc] + biasX[cg * 4 + cc]);
      part += m * vvl[cg * 4 + cc];
    }
    part += __shfl_xor(part, 1);
    part += __shfl_xor(part, 2);
    part += __shfl_xor(part, 4);
    float a2 = mishf(part + cb2);
    if (cg == 0){
      act2[(size_t)blockIdx.x * 256 + rg * 8 + rr] = a2;
      ss += a2; qq += a2 * a2;
    }
  }
  #pragma unroll
  for (int off = 1; off < 64; off <<= 1){ ss += __shfl_xor(ss, off); qq += __shfl_xor(qq, off); }
  int lane = tid & 63, wid = tid >> 6;
  if (lane == 0){ r2s[wid] = ss; r2q[wid] = qq; }
  __syncthreads();
  if (tid == 0){
    atomicAdd(&s2g[blockIdx.x & 15], r2s[0] + r2s[1] + r2s[2] + r2s[3]);
    atomicAdd(&q2g[blockIdx.x & 15], r2q[0] + r2q[1] + r2q[2] + r2q[3]);
  }
}

// ---------------- m2 MLP layer 1 (K-split) ----------------
__global__ __launch_bounds__(512) void k_wmlp1(const float* __restrict__ fpw, const float* __restrict__ W0,
                                               float* __restrict__ wact0){
  int f = blockIdx.x, kc = blockIdx.y, c = threadIdx.x;
  const float* row = fpw + (size_t)f * 4096 + kc * 512;
  const float* wp  = W0 + (size_t)(kc * 512) * 512 + c;
  float acc = 0.0f;
  #pragma unroll 8
  for (int k = 0; k < 512; ++k) acc += row[k] * wp[(size_t)k * 512];
  atomicAdd(&wact0[f * 512 + c], acc);
}

// ---------------- m2 MLP finish ----------------
__global__ __launch_bounds__(512) void k_wmlp2(const float* __restrict__ wact0, const float* __restrict__ b0,
                                               const float* __restrict__ W1,
                                               const float* __restrict__ b1,
                                               const float* __restrict__ g0, const float* __restrict__ be0,
                                               const float* __restrict__ g1, const float* __restrict__ be1,
                                               float* __restrict__ wfin){
  __shared__ float wl[32 * 512];
  __shared__ float o2l[512], A1l[16], C1l[16];
  int t = threadIdx.x;
  {
    float b0t = b0[t];
    float v[32]; float sum = 0.0f, sq = 0.0f;
    #pragma unroll
    for (int r = 0; r < 32; ++r){
      v[r] = mishf(wact0[r * 512 + t] + b0t);
      sum += v[r]; sq += v[r] * v[r];
    }
    float mu  = sum * (1.0f / 32.0f);
    float var = sq * (1.0f / 32.0f) - mu * mu;
    float A = g0[t] * rsqrtf(var + 1e-3f);
    float C = be0[t] - mu * A;
    #pragma unroll
    for (int r = 0; r < 32; ++r) wl[r * 512 + t] = v[r] * A + C;
  }
  __syncthreads();
  {
    int r = t >> 4, c2 = t & 15;
    float pre = b1[c2];
    for (int k = 0; k < 512; ++k) pre += wl[r * 512 + k] * W1[k * 16 + c2];
    o2l[t] = mishf(pre);
  }
  __syncthreads();
  if (t < 16){
    float sum = 0.0f, sq = 0.0f;
    #pragma unroll
    for (int r = 0; r < 32; ++r){ float v = o2l[r * 16 + t]; sum += v; sq += v * v; }
    float mu  = sum * (1.0f / 32.0f);
    float var = sq * (1.0f / 32.0f) - mu * mu;
    float A = g1[t] * rsqrtf(var + 1e-3f);
    A1l[t] = A; C1l[t] = be1[t] - mu * A;
  }
  __syncthreads();
  wfin[t] = o2l[t] * A1l[t & 15] + C1l[t & 15];
}

// ---------------- aggregation + per-point einsum -> fbuf[4096,1024] ----------------
__global__ __launch_bounds__(256) void k_agg(const float* __restrict__ act2, const float* __restrict__ wfin,
                                             const float* __restrict__ x, const int* __restrict__ idxp,
                                             const float* __restrict__ s2, const float* __restrict__ q2,
                                             const float* __restrict__ g2, const float* __restrict__ be2,
                                             float* __restrict__ fbuf){
  __shared__ float hl[512], wfl[512], wm[256], furl[1024], AC[2];
  int t = threadIdx.x;
  int k = blockIdx.x;
  if (t == 0){
    const float invR = 1.0f / (float)RROWS;
    float ssum = 0.0f, qsum = 0.0f;
    #pragma unroll
    for (int b = 0; b < 16; ++b){ ssum += s2[b]; qsum += q2[b]; }
    float mu  = ssum * invR;
    float var = qsum * invR - mu * mu;
    float A = g2[0] * rsqrtf(var + 1e-3f);
    AC[0] = A; AC[1] = be2[0] - mu * A;
  }
  wfl[t] = wfin[t]; wfl[t + 256] = wfin[t + 256];
  __syncthreads();
  float A2 = AC[0], C2 = AC[1];
  hl[t]       = act2[(size_t)k * 512 + t]       * A2 + C2;
  hl[t + 256] = act2[(size_t)k * 512 + 256 + t] * A2 + C2;
  __syncthreads();
  {
    int m = t >> 4, d = t & 15;
    float acc = 0.0f;
    #pragma unroll
    for (int j = 0; j < 32; ++j) acc += hl[m * 32 + j] * wfl[j * 16 + d];
    wm[t] = acc;
  }
  int b = k >> 9;
  const float* xb = x + (size_t)b * (NN * CIN);
  {
    int c = t & 63;
    #pragma unroll
    for (int it = 0; it < 4; ++it){
      int m = it * 4 + (t >> 6);
      int im = idxp[k * 16 + m];
      furl[m * 64 + c] = xb[im * 64 + c];
    }
  }
  __syncthreads();
  {
    int d = t & 15, c0 = t >> 4;
    #pragma unroll
    for (int q = 0; q < 4; ++q){
      int c = c0 + 16 * q;
      float acc = 0.0f;
      #pragma unroll
      for (int m = 0; m < 16; ++m) acc += furl[m * 64 + c] * wm[m * 16 + d];
      fbuf[(size_t)k * 1024 + t + 256 * q] = acc;
    }
  }
}

// ---------------- mr layer 1: bf16 MFMA GEMM [4096,1024]@[1024,512] + mish + stats ----------------
// Fragment layouts mirror the verified k_m1_p2 (A[m=lane&15][k=quad*8+j],
// B[n=lane&15][k], D col=lane&15 / row=quad*4+reg). f32 accumulate.
__global__ __launch_bounds__(256) void k_mr1(const float* __restrict__ F, const float* __restrict__ W,
                                             const float* __restrict__ bias, float* __restrict__ out,
                                             float* __restrict__ s3, float* __restrict__ q3){
  __shared__ __align__(16) ushort_t As[64 * AST];   // [m][k] bf16
  __shared__ __align__(16) ushort_t Bs[64 * AST];   // [n][k] bf16
  __shared__ float csum[64], csq[64];
  int tid = threadIdx.x;
  int m0 = blockIdx.y * 64, n0 = blockIdx.x * 64;
  int lane = tid & 63, w = tid >> 6;
  int ln15 = lane & 15, quad = lane >> 4;
  if (tid < 64){ csum[tid] = 0.0f; csq[tid] = 0.0f; }
  f32x4 acc[4];
  #pragma unroll
  for (int n = 0; n < 4; ++n){ acc[n][0] = 0.0f; acc[n][1] = 0.0f; acc[n][2] = 0.0f; acc[n][3] = 0.0f; }

  #pragma unroll 1
  for (int k0 = 0; k0 < 1024; k0 += 64){
    __syncthreads();
    // stage A tile: rows m0..m0+63, k0..k0+63; thread: row=tid>>2, 16 k each
    {
      int row = tid >> 2, kq = (tid & 3) * 16;
      const float* src = &F[(size_t)(m0 + row) * 1024 + k0 + kq];
      float4 v0 = *(const float4*)&src[0];
      float4 v1 = *(const float4*)&src[4];
      float4 v2 = *(const float4*)&src[8];
      float4 v3 = *(const float4*)&src[12];
      uint4 p0, p1;
      p0.x = (unsigned)f2bf(v0.x) | ((unsigned)f2bf(v0.y) << 16);
      p0.y = (unsigned)f2bf(v0.z) | ((unsigned)f2bf(v0.w) << 16);
      p0.z = (unsigned)f2bf(v1.x) | ((unsigned)f2bf(v1.y) << 16);
      p0.w = (unsigned)f2bf(v1.z) | ((unsigned)f2bf(v1.w) << 16);
      p1.x = (unsigned)f2bf(v2.x) | ((unsigned)f2bf(v2.y) << 16);
      p1.y = (unsigned)f2bf(v2.z) | ((unsigned)f2bf(v2.w) << 16);
      p1.z = (unsigned)f2bf(v3.x) | ((unsigned)f2bf(v3.y) << 16);
      p1.w = (unsigned)f2bf(v3.z) | ((unsigned)f2bf(v3.w) << 16);
      ushort_t* dst = &As[row * AST + kq];
      *(uint4*)&dst[0] = p0;
      *(uint4*)&dst[8] = p1;
    }
    // stage B tile transposed: Bs[n][k] = W[k0+k][n0+n]
    #pragma unroll
    for (int rr = 0; rr < 4; ++rr){
      int kk = rr * 16 + (tid >> 4);
      int nn = (tid & 15) * 4;
      float4 v = *(const float4*)&W[(size_t)(k0 + kk) * 512 + n0 + nn];
      Bs[(nn + 0) * AST + kk] = f2bf(v.x);
      Bs[(nn + 1) * AST + kk] = f2bf(v.y);
      Bs[(nn + 2) * AST + kk] = f2bf(v.z);
      Bs[(nn + 3) * AST + kk] = f2bf(v.w);
    }
    __syncthreads();
    #pragma unroll
    for (int ks = 0; ks < 64; ks += 32){
      bf16x8 af = *(bf16x8*)&As[(w * 16 + ln15) * AST + ks + quad * 8];
      #pragma unroll
      for (int n = 0; n < 4; ++n){
        bf16x8 bfv = *(bf16x8*)&Bs[(n * 16 + ln15) * AST + ks + quad * 8];
        acc[n] = __builtin_amdgcn_mfma_f32_16x16x32_bf16(af, bfv, acc[n], 0, 0, 0);
      }
    }
  }
  // epilogue: bias + mish + store f32 + column stats
  #pragma unroll
  for (int n = 0; n < 4; ++n){
    int col = n0 + n * 16 + ln15;
    float bv = bias[col];
    f32x4 a = acc[n];
    float s = 0.0f, q = 0.0f;
    #pragma unroll
    for (int r = 0; r < 4; ++r){
      float v = mishf(a[r] + bv);
      int row = m0 + w * 16 + quad * 4 + r;
      out[(size_t)row * 512 + col] = v;
      s += v; q += v * v;
    }
    s += __shfl_xor(s, 16); q += __shfl_xor(q, 16);
    s += __shfl_xor(s, 32); q += __shfl_xor(q, 32);
    if (quad == 0){
      atomicAdd(&csum[n * 16 + ln15], s);
      atomicAdd(&csq[n * 16 + ln15], q);
    }
  }
  __syncthreads();
  if (tid < 64){
    atomicAdd(&s3[n0 + tid], csum[tid]);
    atomicAdd(&q3[n0 + tid], csq[tid]);
  }
}

// ---------------- mr layer 2: bn -> f32 tiled GEMM + mish + stats ----------------
__global__ __launch_bounds__(256) void k_mr2(const float* __restrict__ Ain, const float* __restrict__ W,
                                             const float* __restrict__ bias,
                                             const float* __restrict__ s3, const float* __restrict__ q3,
                                             const float* __restrict__ g0, const float* __restrict__ be0,
                                             float* __restrict__ out, float* __restrict__ s4, float* __restrict__ q4){
  __shared__ float As2[16][68];
  __shared__ float Bs2[16][68];
  __shared__ float A3l[512], C3l[512];
  __shared__ float csum[64], csq[64];
  int tid = threadIdx.x;
  for (int kk = tid; kk < 512; kk += 256){
    const float invR = 1.0f / 4096.0f;
    float mu  = s3[kk] * invR;
    float var = q3[kk] * invR - mu * mu;
    float A = g0[kk] * rsqrtf(var + 1e-3f);
    A3l[kk] = A; C3l[kk] = be0[kk] - mu * A;
  }
  if (tid < 64){ csum[tid] = 0.0f; csq[tid] = 0.0f; }
  __syncthreads();
  int m0 = blockIdx.x * 64;
  int tx = tid & 15, ty = tid >> 4;
  float acc[4][4];
  #pragma unroll
  for (int i = 0; i < 4; ++i)
    #pragma unroll
    for (int j = 0; j < 4; ++j) acc[i][j] = 0.0f;
  int lmm = tid >> 2, lkq = (tid & 3) * 4;
  int lkk = tid >> 4, lnq = (tid & 15) * 4;
  float4 av = *(const float4*)&Ain[(size_t)(m0 + lmm) * 512 + lkq];
  float4 bv = *(const float4*)&W[(size_t)lkk * 64 + lnq];
  for (int k0 = 0; k0 < 512; k0 += 16){
    As2[lkq + 0][lmm] = av.x * A3l[k0 + lkq + 0] + C3l[k0 + lkq + 0];
    As2[lkq + 1][lmm] = av.y * A3l[k0 + lkq + 1] + C3l[k0 + lkq + 1];
    As2[lkq + 2][lmm] = av.z * A3l[k0 + lkq + 2] + C3l[k0 + lkq + 2];
    As2[lkq + 3][lmm] = av.w * A3l[k0 + lkq + 3] + C3l[k0 + lkq + 3];
    *(float4*)&Bs2[lkk][lnq] = bv;
    __syncthreads();
    if (k0 + 16 < 512){
      av = *(const float4*)&Ain[(size_t)(m0 + lmm) * 512 + (k0 + 16) + lkq];
      bv = *(const float4*)&W[(size_t)((k0 + 16) + lkk) * 64 + lnq];
    }
    #pragma unroll
    for (int kk = 0; kk < 16; ++kk){
      float4 a4 = *(const float4*)&As2[kk][ty * 4];
      float4 b4 = *(const float4*)&Bs2[kk][tx * 4];
      float a[4] = {a4.x, a4.y, a4.z, a4.w};
      float bb[4] = {b4.x, b4.y, b4.z, b4.w};
      #pragma unroll
      for (int i = 0; i < 4; ++i)
        #pragma unroll
        for (int j = 0; j < 4; ++j) acc[i][j] += a[i] * bb[j];
    }
    __syncthreads();
  }
  float4 bq = *(const float4*)&bias[tx * 4];
  float bvs[4] = {bq.x, bq.y, bq.z, bq.w};
  float cs[4] = {0,0,0,0}, cq[4] = {0,0,0,0};
  #pragma unroll
  for (int i = 0; i < 4; ++i){
    float v[4];
    #pragma unroll
    for (int j = 0; j < 4; ++j){
      v[j] = mishf(acc[i][j] + bvs[j]);
      cs[j] += v[j]; cq[j] += v[j] * v[j];
    }
    float4 o = make_float4(v[0], v[1], v[2], v[3]);
    *(float4*)&out[(size_t)(m0 + ty * 4 + i) * 64 + tx * 4] = o;
  }
  #pragma unroll
  for (int j = 0; j < 4; ++j){
    float v = cs[j], w = cq[j];
    v += __shfl_xor(v, 16); w += __shfl_xor(w, 16);
    v += __shfl_xor(v, 32); w += __shfl_xor(w, 32);
    if ((tid & 63) < 16){
      atomicAdd(&csum[tx * 4 + j], v);
      atomicAdd(&csq[tx * 4 + j], w);
    }
  }
  __syncthreads();
  if (tid < 64){
    atomicAdd(&s4[tid], csum[tid]);
    atomicAdd(&q4[tid], csq[tid]);
  }
}

// ---------------- final BN -> output ----------------
__global__ __launch_bounds__(256) void k_out(const float* __restrict__ pre,
                                             const float* __restrict__ s4, const float* __restrict__ q4,
                                             const float* __restrict__ g1, const float* __restrict__ be1,
                                             float* __restrict__ outp){
  int e = blockIdx.x * 256 + threadIdx.x;
  int c = e & 63;
  const float invR = 1.0f / 4096.0f;
  float mu  = s4[c] * invR;
  float var = q4[c] * invR - mu * mu;
  float A = g1[c] * rsqrtf(var + 1e-3f);
  outp[e] = pre[e] * A + (be1[c] - mu * A);
}

// ---------------- launcher ----------------
extern "C" void kernel_launch(void* const* d_in, const int* in_sizes, int n_in,
                              void* d_out, int out_size, void* d_ws, size_t ws_size,
                              hipStream_t stream){
  (void)in_sizes; (void)n_in; (void)out_size;
  const float* x    = (const float*)d_in[0];
  const float* xyz  = (const float*)d_in[1];
  const float* fpts = (const float*)d_in[2];
  const float* fpw  = (const float*)d_in[3];
  const float* m1w0 = (const float*)d_in[4];
  const float* m1b0 = (const float*)d_in[5];
  const float* m1g0 = (const float*)d_in[6];
  const float* m1be0= (const float*)d_in[7];
  const float* m1w1 = (const float*)d_in[8];
  const float* m1b1 = (const float*)d_in[9];
  const float* m1g1 = (const float*)d_in[10];
  const float* m1be1= (const float*)d_in[11];
  const float* m1w2 = (const float*)d_in[12];
  const float* m1b2 = (const float*)d_in[13];
  const float* m1g2 = (const float*)d_in[14];
  const float* m1be2= (const float*)d_in[15];
  const float* m2w0 = (const float*)d_in[16];
  const float* m2b0 = (const float*)d_in[17];
  const float* m2g0 = (const float*)d_in[18];
  const float* m2be0= (const float*)d_in[19];
  const float* m2w1 = (const float*)d_in[20];
  const float* m2b1 = (const float*)d_in[21];
  const float* m2g1 = (const float*)d_in[22];
  const float* m2be1= (const float*)d_in[23];
  const float* mrw0 = (const float*)d_in[24];
  const float* mrb0 = (const float*)d_in[25];
  const float* mrg0 = (const float*)d_in[26];
  const float* mrbe0= (const float*)d_in[27];
  const float* mrw1 = (const float*)d_in[28];
  const float* mrb1 = (const float*)d_in[29];
  const float* mrg1 = (const float*)d_in[30];
  const float* mrbe1= (const float*)d_in[31];

  float* wsf = (float*)d_ws;
  float* s0 = wsf + 0;     float* q0 = wsf + 512;
  float* s1 = wsf + 1024;  float* q1 = wsf + 1536;
  float* s2 = wsf + 2048;  float* q2 = wsf + 2064;
  float* s3 = wsf + 2080;  float* q3 = wsf + 2592;
  float* s4 = wsf + 3104;  float* q4 = wsf + 3168;
  int*   idxp = (int*)(wsf + 4096);        // 65536 ints -> ends 69632
  double* sqd = (double*)(wsf + 69632);    // 4096 f64 = 8192 floats -> ends 77824
  float* wact0= wsf + 332032;              // 32*512 pre-activation accumulator
  float* wfin = wsf + 348416;              // 32*16
  float* act2 = wsf + 348928;              // 2098176
  float* fbuf = wsf + 2447104;             // 4096*1024 (hosts sib/fjt early)
  float* sib  = fbuf;                      // 65568*32
  float* fjt  = fbuf + 2098176;            // 1024
  float* mact = wsf + 6641408;             // 4096*512
  float* mact2= wsf + 8738560;             // 4096*64  (ends 9000704 floats = 36 MB)

  size_t need = 9000704ULL * 4 + (size_t)RROWS * 32 * 2;
  bool fast = (ws_size >= need);
  ushort_t* a1b = fast ? (ushort_t*)(wsf + 9000704) : nullptr;   // col-major [32][RROWS] bf16

  hipMemsetAsync(d_ws, 0, 4096 * sizeof(float), stream);
  hipMemsetAsync(wact0, 0, 16384 * sizeof(float), stream);

  k_sq<<<16, 256, 0, stream>>>(x, sqd);
  k_topk<<<1024, 256, 0, stream>>>(x, sqd, idxp);
  k_prep<<<257, 256, 0, stream>>>(xyz, fpts, idxp, m1w0, m1b0, sib, fjt);
  k_m1_p1<<<1025, 256, 0, stream>>>(sib, fjt, s0, q0);
  k_m1_p2<<<8196, 256, 0, stream>>>(sib, fjt, m1w1, m1b1, m1g0, m1be0, s0, q0, s1, q1, a1b);
  if (fast){
    k_m1_p3s<<<4098, 256, 0, stream>>>(a1b, m1w2, m1b2, m1g1, m1be1, s1, q1, act2, s2, q2);
  } else {
    k_m1_p3f<<<8196, 256, 0, stream>>>(sib, fjt, m1w1, m1b1, m1g0, m1be0, m1g1, m1be1,
                                       m1w2, m1b2, s0, q0, s1, q1, act2, s2, q2);
  }
  k_wmlp1<<<dim3(32, 8), 512, 0, stream>>>(fpw, m2w0, wact0);
  k_wmlp2<<<1, 512, 0, stream>>>(wact0, m2b0, m2w1, m2b1, m2g0, m2be0, m2g1, m2be1, wfin);
  k_agg<<<4096, 256, 0, stream>>>(act2, wfin, x, idxp, s2, q2, m1g2, m1be2, fbuf);
  k_mr1<<<dim3(8, 64), 256, 0, stream>>>(fbuf, mrw0, mrb0, mact, s3, q3);
  k_mr2<<<64, 256, 0, stream>>>(mact, mrw1, mrb1, s3, q3, mrg0, mrbe0, mact2, s4, q4);
  k_out<<<1024, 256, 0, stream>>>(mact2, s4, q4, mrg1, mrbe1, (float*)d_out);
}